// Round 19
// baseline (41.523 us; speedup 1.0000x reference)
//
#include <hip/hip_runtime.h>

#define EPSLN 1e-5f
#define KMINC 9
#define SLI   10         // slices per (b,i), 8 rows each -> covers n <= 80

typedef _Float16 h2 __attribute__((ext_vector_type(2)));
typedef _Float16 h4 __attribute__((ext_vector_type(4)));

#if defined(__has_builtin)
#if __has_builtin(__builtin_amdgcn_fdot2)
#define FDOT2(a,b,c) __builtin_amdgcn_fdot2((a),(b),(c),false)
#endif
#endif
#ifndef FDOT2
#define FDOT2(a,b,c) ((c) + (float)(a)[0]*(float)(b)[0] + (float)(a)[1]*(float)(b)[1])
#endif

__device__ __forceinline__ h2 mk2(float a, float b){
  h2 v; v[0]=(_Float16)a; v[1]=(_Float16)b; return v;
}
__device__ __forceinline__ unsigned h2bits(h2 v){
  union { h2 h; unsigned u; } c; c.h = v; return c.u;
}
__device__ __forceinline__ h2 asH2(unsigned u){
  union { unsigned u; h2 h; } c; c.u = u; return c.h;
}

// ---- DPP-based reductions (r17-verified): butterflies on the VALU pipe ----
template<int CTRL>
__device__ __forceinline__ float dppadd(float v){
  union { float f; int i; } a, r;
  a.f = v;
  r.i = __builtin_amdgcn_update_dpp(a.i, a.i, CTRL, 0xf, 0xf, true);
  return v + r.f;
}
__device__ __forceinline__ float wred16d(float v){
  v = dppadd<0x0B1>(v);
  v = dppadd<0x04E>(v);
  v = dppadd<0x124>(v);
  v = dppadd<0x128>(v);
  return v;
}
__device__ __forceinline__ float wred32(float v){
  v = wred16d(v);
  return v + __shfl_xor(v, 16, 64);
}
__device__ __forceinline__ float wred64(float v){
  v = wred16d(v);
  v += __shfl_xor(v, 16, 64);
  return v + __shfl_xor(v, 32, 64);
}

// ws word-offsets
#define WS_NODE   0
#define WS_CNT    16384
#define WS_JLIST  16896       // 512*96 ints
#define WS_M0B    66048       // 512*16 f32
#define WS_PART   74240       // 512*SLI*28 f32 = 143360
#define WS_PACKW  217600      // q-blocked packed weights (3552 u32)

// ---------------- Kernel P: msa-LN/attention/node + m0b + top-k mask + weight packing ----------------
// grid = B*L (512), block = 512 (8 waves). Phase-2 rank scan split across both halves:
// lower half (tid<256) keeps its partial IN REGISTER (it continues to compaction);
// upper half deposits its partial in rankS; one barrier; add. (r18 race fixed: no Dv overwrite.)
__global__ __launch_bounds__(512) void k_prep(
    const float* __restrict__ msa, const float* __restrict__ seq1hot,
    const float* __restrict__ xyz, const int* __restrict__ idxp,
    const int* __restrict__ topk,
    const float* __restrict__ g_msa, const float* __restrict__ b_msa,
    const float* __restrict__ Wq, const float* __restrict__ bq,
    const float* __restrict__ Wk, const float* __restrict__ bk,
    const float* __restrict__ Wx, const float* __restrict__ bx,
    const float* __restrict__ g_node, const float* __restrict__ b_node,
    const float* __restrict__ We, const float* __restrict__ Wa,
    const float* __restrict__ W0, const float* __restrict__ b0,
    const float* __restrict__ Wc1, const float* __restrict__ Wc2,
    float* __restrict__ node, int* __restrict__ cnt, int* __restrict__ jlist,
    float* __restrict__ m0bG, unsigned* __restrict__ packW)
{
  const int bid = blockIdx.x;          // b*256 + l  (l == i)
  const int b = bid >> 8;
  const int tid = threadIdx.x;
  const int w = tid >> 6, lane = tid & 63;   // 8 waves

  __shared__ float mn[32][64];
  __shared__ float qS[64];
  __shared__ float scS[32];
  __shared__ float redS[8][64];
  __shared__ float ssumS[8];
  __shared__ float nodeS[32];
  __shared__ alignas(16) float Dv[256];
  __shared__ int   rankS[256];
  __shared__ int   wsum[4];

  // ---- block 0 packs weights q-blocked f16 into ws (for k_main) ----
  if (bid==0){
    for (int i=tid;i<2048;i+=512){
      int qb=i>>7, r7=i&127, t=r7>>2, i2=r7&3, q=4*qb+i2;
      packW[i] = h2bits(mk2(We[(2*q)*32+t], We[(2*q+1)*32+t]));
    }
    for (int i=tid;i<512; i+=512){
      int qb=i>>7, r7=i&127, t=r7>>2, i2=r7&3, q=4*qb+i2;
      packW[2048+i] = h2bits(mk2(Wa[(2*q)*32+t], Wa[(2*q+1)*32+t]));
    }
    for (int i=tid;i<768; i+=512){
      int qb=i>>6, r6=i&63, tc=r6>>2, i2=r6&3, q=4*qb+i2;
      packW[2560+i] = h2bits(mk2(W0[(2*q)*16+tc], W0[(2*q+1)*16+tc]));
    }
    if (tid<192){
      int qb=tid/48, r48=tid%48, tc=r48>>2, i2=r48&3, q=4*qb+i2;
      float lo = (tc<3)? Wc1[(2*q)*3+tc]   : Wc2[(2*q)*9+(tc-3)];
      float hi = (tc<3)? Wc1[(2*q+1)*3+tc] : Wc2[(2*q+1)*9+(tc-3)];
      packW[3328+tid] = h2bits(mk2(lo,hi));
    }
    if (tid<32) ((float*)packW)[3520+tid] = Wa[32*32+tid];
  }

  // ---- msa LN: wave w rows w, w+8, w+16, w+24 ----
  const float gm = g_msa[lane], bm = b_msa[lane];
  for (int nn=w; nn<32; nn+=8){
    float x = msa[(size_t)(((b*32+nn)<<8)+(bid&255))*64 + lane];
    float s = wred64(x), s2 = wred64(x*x);
    float mu = s*(1.f/64.f);
    float var = s2*(1.f/64.f) - mu*mu;
    mn[nn][lane] = (x-mu)*rsqrtf(var+EPSLN)*gm + bm;
  }
  __syncthreads();
  // ---- q[e=lane]: partial over d-range per wave ----
  {
    float p = (w==0)? bq[lane] : 0.f;
    for (int d=w*8; d<w*8+8; d++) p += mn[0][d]*Wq[d*64+lane];
    redS[w][lane] = p;
  }
  __syncthreads();
  if (w==0){
    float q = 0.f;
    #pragma unroll
    for (int k=0;k<8;k++) q += redS[k][lane];
    qS[lane] = q*0.125f;               // 1/sqrt(64)
  }
  __syncthreads();
  // ---- qk[d=lane]: partial over e-range per wave ----
  {
    float p = 0.f;
    for (int e=w*8; e<w*8+8; e++) p += Wk[lane*64+e]*qS[e];
    redS[w][lane] = p;
  }
  __syncthreads();
  float qk = 0.f;
  #pragma unroll
  for (int k=0;k<8;k++) qk += redS[k][lane];
  const float qb_ = wred64(qS[lane]*bk[lane]);
  // ---- scores: wave w rows w*4..w*4+3 ----
  for (int nn=w*4; nn<w*4+4; nn++){
    float p = wred64(mn[nn][lane]*qk);
    if (lane==0) scS[nn] = p + qb_;
  }
  __syncthreads();
  // ---- softmax + weighted msa ----
  float mx = -1e30f;
  for (int nn=0; nn<32; nn++) mx = fmaxf(mx, scS[nn]);
  float ps=0.f, pm=0.f;
  for (int nn=w*4; nn<w*4+4; nn++){
    float e = expf(scS[nn]-mx);
    ps += e; pm += e*mn[nn][lane];
  }
  redS[w][lane] = pm;
  if (lane==0) ssumS[w] = ps;
  __syncthreads();
  if (w==0){
    float ssum = 0.f, acc = 0.f;
    #pragma unroll
    for (int k=0;k<8;k++){ ssum += ssumS[k]; acc += redS[k][lane]; }
    qS[lane] = acc / ssum;
  }
  __syncthreads();
  if (tid<32){
    float acc = bx[tid];
    for (int k=0;k<64;k++) acc += qS[k]*Wx[k*32+tid];
    const float* s1 = &seq1hot[bid*21];
    for (int k=0;k<21;k++) acc += s1[k]*Wx[(64+k)*32+tid];
    float s = wred32(acc), s2 = wred32(acc*acc);
    float mu = s*(1.f/32.f), var = s2*(1.f/32.f)-mu*mu;
    float v = (acc-mu)*rsqrtf(var+EPSLN)*g_node[tid] + b_node[tid];
    node[bid*32+tid] = v;
    nodeS[tid] = v;
  }
  __syncthreads();
  if (tid<16){
    float acc = b0[tid];
    for (int k=0;k<32;k++) acc += nodeS[k]*W0[(32+k)*16+tid];
    m0bG[bid*16+tid] = acc;
  }

  // --- Phase 2: distances + split rank scan (both halves, race-free) + compaction ---
  const bool act = tid < 256;
  const int i = bid & 255;
  const int j8 = tid & 255;            // j for this thread (both halves share j8)
  float D = 0.f;
  if (act){
    const float cax = xyz[(bid*3+1)*3+0];
    const float cay = xyz[(bid*3+1)*3+1];
    const float caz = xyz[(bid*3+1)*3+2];
    const int jb = (b<<8)+j8;
    float dx = xyz[(jb*3+1)*3+0]-cax;
    float dy = xyz[(jb*3+1)*3+1]-cay;
    float dz = xyz[(jb*3+1)*3+2]-caz;
    D = sqrtf(dx*dx+dy*dy+dz*dz) + (i==j8 ? 999.9f : 0.f);
  }
  __syncthreads();
  if (act) Dv[j8] = D;
  __syncthreads();
  // both halves scan half the Dv range for the same j8; lower keeps its partial in
  // a register, upper deposits in rankS. No Dv writes here (r18 race fix).
  int rankLo = 0;
  {
    const float Dj = Dv[j8];
    const int base = (tid >> 8) * 128;     // 0 for lower half, 128 for upper half
    int rank = 0;
    for (int j2=base; j2<base+128; j2+=4){
      const float4 dv = *(const float4*)&Dv[j2];
      rank += (dv.x < Dj || (dv.x == Dj && (j2+0) < j8)) ? 1 : 0;
      rank += (dv.y < Dj || (dv.y == Dj && (j2+1) < j8)) ? 1 : 0;
      rank += (dv.z < Dj || (dv.z == Dj && (j2+2) < j8)) ? 1 : 0;
      rank += (dv.w < Dj || (dv.w == Dj && (j2+3) < j8)) ? 1 : 0;
    }
    if (!act) rankS[j8] = rank;            // upper half deposits its partial
    else      rankLo = rank;               // lower half keeps it in register
  }
  __syncthreads();
  if (act){
    const int rank = rankLo + rankS[j8];
    int K = topk[0];
    if (K<=0 || K>256){
      float f = ((const float*)topk)[0];
      K = (f>=1.f && f<=256.f) ? (int)f : 64;
    }
    const int jb = (b<<8)+j8;
    const int sep = abs(idxp[jb] - idxp[bid]);
    const bool m = (rank < K) || (i!=j8 && sep < KMINC);
    unsigned long long bal = __ballot(m);
    const int l6 = j8 & 63, wv = j8 >> 6;
    const int pre = __popcll(bal & ((1ull<<l6)-1ull));
    if (l6==0) wsum[wv] = __popcll(bal);
    __syncthreads();
    int off = 0;
    for (int w2=0;w2<wv;w2++) off += wsum[w2];
    if (m) jlist[bid*96 + off + pre] = j8;
    if (j8==0) cnt[bid] = wsum[0]+wsum[1]+wsum[2]+wsum[3];
  } else {
    __syncthreads();
  }
}

// ---------------- Kernel C: wave-per-slice gathered pipeline, b128 LDS (r17-verified) ----------------
// grid = 512*SLI/4 (1280), block = 256 = 4 independent waves; wave = one 8-row slice.
__global__ __launch_bounds__(256) void k_main(
    const float* __restrict__ pair, const float* __restrict__ xyz,
    const float* __restrict__ g_pair, const float* __restrict__ b_pair,
    const float* __restrict__ be, const float* __restrict__ g_edge,
    const float* __restrict__ b_edge, const float* __restrict__ ba,
    const float* __restrict__ node, const int* __restrict__ cnt,
    const int* __restrict__ jlist, const float* __restrict__ m0bG,
    const unsigned* __restrict__ packW, float* __restrict__ part)
{
  const int tid = threadIdx.x;
  const int w  = tid >> 6;          // wave 0..3
  const int wl = tid & 63;          // lane in wave
  const int r  = (tid >> 5) & 1;    // group in wave
  const int t  = tid & 31;          // lane in group

  __shared__ alignas(16) unsigned WeL[2048];        // 8 KB q-blocked
  __shared__ alignas(16) unsigned WaL[512];         // 2 KB
  __shared__ alignas(16) unsigned W0L[768];         // 3 KB
  __shared__ alignas(16) unsigned WcL[192];         // 768 B
  __shared__ float waD[32];
  __shared__ float beS[32], geS[32], beeS[32], baS[32];
  __shared__ alignas(16) _Float16 pnH[32][128];     // 8 KB
  __shared__ alignas(16) _Float16 edH[32][32];      // 2 KB
  __shared__ alignas(16) _Float16 aH [32][32];      // 2 KB
  __shared__ alignas(16) _Float16 ndH[32][32];      // 2 KB
  __shared__ float cS[32*12];
  __shared__ float xjS[32][9];
  __shared__ float geoS[32][4];

  // ---- vectorized weight copy (uint4) ----
  {
    const uint4* p4 = (const uint4*)packW;
    #pragma unroll
    for (int i2=tid;i2<512;i2+=256) ((uint4*)WeL)[i2] = p4[i2];
    if (tid<128) ((uint4*)WaL)[tid] = p4[512+tid];
    if (tid<192) ((uint4*)W0L)[tid] = p4[640+tid];
    if (tid<48)  ((uint4*)WcL)[tid] = p4[832+tid];
  }
  if (tid<32){
    waD[tid] = ((const float*)packW)[3520+tid];
    beS[tid]=be[tid]; geS[tid]=g_edge[tid]; beeS[tid]=b_edge[tid]; baS[tid]=ba[tid];
  }
  __syncthreads();        // the ONLY block-wide barrier

  const int s    = blockIdx.x*4 + w;   // slice id
  const int item = s / SLI;            // (b,i)
  const int sl   = s - item*SLI;
  const int b    = item >> 8;
  const int n    = cnt[item];
  const int row0 = sl*8;
  const int wrow = w*8;

  float stA = 0.f;
  float ofA = 0.f;

  if (row0 < n){
    const float cax = xyz[(item*3+1)*3+0];
    const float cay = xyz[(item*3+1)*3+1];
    const float caz = xyz[(item*3+1)*3+2];
    bool vals[4];
    // ---- stage 4 rows per group ----
    {
      const float4 gp4 = *(const float4*)&g_pair[4*t];
      const float4 bp4 = *(const float4*)&b_pair[4*t];
      #pragma unroll
      for (int jc=0;jc<4;jc++){
        const int slot = row0 + r*4 + jc;
        vals[jc] = slot < n;
        const int jj = vals[jc] ? jlist[item*96 + slot] : 0;
        const int row = wrow + r*4 + jc;
        const float* prow = &pair[((long)item*256 + jj)*128];
        const float4 pv4 = *(const float4*)&prow[4*t];
        float sm  = wred32(pv4.x+pv4.y+pv4.z+pv4.w);
        float sm2 = wred32(pv4.x*pv4.x+pv4.y*pv4.y+pv4.z*pv4.z+pv4.w*pv4.w);
        float mu = sm*(1.f/128.f);
        float var = sm2*(1.f/128.f)-mu*mu;
        float rs = rsqrtf(var+EPSLN);
        h4 o;
        o[0]=(_Float16)((pv4.x-mu)*rs*gp4.x+bp4.x);
        o[1]=(_Float16)((pv4.y-mu)*rs*gp4.y+bp4.y);
        o[2]=(_Float16)((pv4.z-mu)*rs*gp4.z+bp4.z);
        o[3]=(_Float16)((pv4.w-mu)*rs*gp4.w+bp4.w);
        *(h4*)&pnH[row][4*t] = o;
        const int jb=(b<<8)+jj;
        ndH[row][t] = (_Float16)node[jb*32+t];
        if (t<9) xjS[row][t] = xyz[(size_t)jb*9 + t];
        if (t==0){
          float jx = xyz[(size_t)jb*9+3]-cax;
          float jy = xyz[(size_t)jb*9+4]-cay;
          float jz = xyz[(size_t)jb*9+5]-caz;
          geoS[row][0]=jx; geoS[row][1]=jy; geoS[row][2]=jz;
          geoS[row][3]=sqrtf(jx*jx+jy*jy+jz*jz);
        }
      }
    }
    // ---- edge GEMV (128->32): 16 iters, all-b128 ----
    float ea0[4], ea1[4];
    #pragma unroll
    for (int jc=0;jc<4;jc++){ ea0[jc]=beS[t]; ea1[jc]=0.f; }
    for (int qb=0; qb<16; ++qb){
      const uint4 wv = *(const uint4*)&WeL[qb*128 + t*4];
      #pragma unroll
      for (int jc=0;jc<4;jc++){
        const uint4 pv = *(const uint4*)&pnH[wrow + r*4 + jc][8*qb];
        ea0[jc]=FDOT2(asH2(wv.y), asH2(pv.y), FDOT2(asH2(wv.x), asH2(pv.x), ea0[jc]));
        ea1[jc]=FDOT2(asH2(wv.w), asH2(pv.w), FDOT2(asH2(wv.z), asH2(pv.z), ea1[jc]));
      }
    }
    // ---- edge LN -> edH f16 ----
    #pragma unroll
    for (int jc=0;jc<4;jc++){
      float acc=ea0[jc]+ea1[jc];
      float sm=wred32(acc), sm2=wred32(acc*acc);
      float mu=sm*(1.f/32.f), var=sm2*(1.f/32.f)-mu*mu;
      edH[wrow + r*4 + jc][t] = (_Float16)((acc-mu)*rsqrtf(var+EPSLN)*geS[t]+beeS[t]);
    }
    // ---- a = relu([edge, dist] @ Wa + ba) ----
    float av[4];
    #pragma unroll
    for (int jc=0;jc<4;jc++) av[jc]=baS[t]+geoS[wrow + r*4 + jc][3]*waD[t];
    for (int qb=0; qb<4; ++qb){
      const uint4 wv = *(const uint4*)&WaL[qb*128 + t*4];
      #pragma unroll
      for (int jc=0;jc<4;jc++){
        const uint4 ev = *(const uint4*)&edH[wrow + r*4 + jc][8*qb];
        av[jc]=FDOT2(asH2(wv.w), asH2(ev.w), FDOT2(asH2(wv.z), asH2(ev.z),
                FDOT2(asH2(wv.y), asH2(ev.y), FDOT2(asH2(wv.x), asH2(ev.x), av[jc]))));
      }
    }
    #pragma unroll
    for (int jc=0;jc<4;jc++) aH[wrow + r*4 + jc][t]=(_Float16)fmaxf(av[jc],0.f);
    // ---- m0: a-part lanes t<16 (W0 blocks 0..3), node-part t>=16 (blocks 8..11) ----
    {
      const int half = t>>4, tc = t&15;
      const int wb = half ? 8 : 0;
      const float m0b = half ? 0.f : m0bG[item*16+tc];
      float m0v[4];
      #pragma unroll
      for (int jc=0;jc<4;jc++) m0v[jc]=m0b;
      for (int qb=0;qb<4;++qb){
        const uint4 wv = *(const uint4*)&W0L[(wb+qb)*64 + tc*4];
        #pragma unroll
        for (int jc=0;jc<4;jc++){
          const _Float16* opb = half ? &ndH[wrow + r*4 + jc][0] : &aH[wrow + r*4 + jc][0];
          const uint4 ov = *(const uint4*)&opb[8*qb];
          m0v[jc]=FDOT2(asH2(wv.w), asH2(ov.w), FDOT2(asH2(wv.z), asH2(ov.z),
                   FDOT2(asH2(wv.y), asH2(ov.y), FDOT2(asH2(wv.x), asH2(ov.x), m0v[jc]))));
        }
      }
      #pragma unroll
      for (int jc=0;jc<4;jc++){
        float tot = m0v[jc] + __shfl_xor(m0v[jc], 16);
        if (t<16 && vals[jc]) stA += fmaxf(tot, 0.f);
      }
    }
    // ---- c1/c2 from a: lanes t<12 k-rows 0..15 (blocks 0..1), lanes 12..23 k 16..31 (blocks 2..3) ----
    {
      const bool up = (t>=12 && t<24);
      const int tc12 = up ? t-12 : (t<12 ? t : 0);
      const int wb = up ? 2 : 0;
      const int koff = up ? 16 : 0;
      float cv[4]={0.f,0.f,0.f,0.f};
      for (int qb=0;qb<2;++qb){
        const uint4 wv = *(const uint4*)&WcL[(wb+qb)*48 + tc12*4];
        #pragma unroll
        for (int jc=0;jc<4;jc++){
          const uint4 av2 = *(const uint4*)&aH[wrow + r*4 + jc][koff + 8*qb];
          cv[jc]=FDOT2(asH2(wv.w), asH2(av2.w), FDOT2(asH2(wv.z), asH2(av2.z),
                  FDOT2(asH2(wv.y), asH2(av2.y), FDOT2(asH2(wv.x), asH2(av2.x), cv[jc]))));
        }
      }
      #pragma unroll
      for (int jc=0;jc<4;jc++){
        const int src = (t<12) ? t+12 : (up ? t-12 : t);
        float other = __shfl(cv[jc], src, 32);
        if (t<12) cS[(wrow + r*4 + jc)*12+t] = cv[jc]+other;
      }
    }
    // ---- offset accumulation (t<9) ----
    if (t<9){
      const int o=t/3, x=t-o*3;
      #pragma unroll
      for (int jc=0;jc<4;jc++){
        if (!vals[jc]) continue;
        const int row = wrow + r*4 + jc;
        const float dj = geoS[row][3];
        const float dh = geoS[row][x]/(dj+1e-8f);
        const float* cr = &cS[row*12];
        float val = cr[o]*dh;
        const float caxj = xjS[row][3+x];
        #pragma unroll
        for (int c=0;c<3;c++){
          val += cr[3+o*3+c]*(xjS[row][c*3+x]-caxj);
        }
        ofA += val;
      }
    }
  }

  stA += __shfl_xor(stA, 32);
  ofA += __shfl_xor(ofA, 32);
  if (wl < 16) part[s*28 + wl] = stA;
  if (wl < 9)  part[s*28 + 16 + wl] = ofA;
}

// ---------------- Kernel F: combine partials, scale by deg, form xyz_new ----------------
// grid = B*L (512), block = 64
__global__ __launch_bounds__(64) void k_fin(
    const float* __restrict__ xyz, const int* __restrict__ cnt,
    const float* __restrict__ part, float* __restrict__ out)
{
  const int bid = blockIdx.x;
  const int t = threadIdx.x;
  __shared__ float offF[9];
  const int n = cnt[bid];
  const float invd = 1.f/fmaxf((float)n,1.f);
  if (t<16){
    float s=0.f;
    #pragma unroll
    for (int k2=0;k2<SLI;k2++) s += part[(bid*SLI+k2)*28 + t];
    out[4608 + bid*16 + t] = s*invd;           // state
  } else if (t<25){
    float s=0.f;
    #pragma unroll
    for (int k2=0;k2<SLI;k2++) s += part[(bid*SLI+k2)*28 + t];
    offF[t-16] = s*invd;
  }
  __syncthreads();
  if (t<9){
    const int o=t/3, x=t-o*3;
    const float cac = xyz[(bid*3+1)*3+x];
    const float CA = cac + offF[3+x];          // offset[:,:,1]
    const float v = (o==1)? CA : (CA + offF[o*3+x]);
    out[bid*9 + t] = v;                        // xyz_new
  }
}

extern "C" void kernel_launch(void* const* d_in, const int* in_sizes, int n_in,
                              void* d_out, int out_size, void* d_ws, size_t ws_size,
                              hipStream_t stream)
{
  const float* msa     = (const float*)d_in[0];
  const float* pair    = (const float*)d_in[1];
  const float* xyz     = (const float*)d_in[2];
  const float* seq1hot = (const float*)d_in[3];
  const float* g_msa   = (const float*)d_in[4];
  const float* b_msa   = (const float*)d_in[5];
  const float* g_pair  = (const float*)d_in[6];
  const float* b_pair  = (const float*)d_in[7];
  const float* Wq      = (const float*)d_in[8];
  const float* bq      = (const float*)d_in[9];
  const float* Wk      = (const float*)d_in[10];
  const float* bk      = (const float*)d_in[11];
  const float* Wx      = (const float*)d_in[12];
  const float* bx      = (const float*)d_in[13];
  const float* g_node  = (const float*)d_in[14];
  const float* b_node  = (const float*)d_in[15];
  const float* We      = (const float*)d_in[16];
  const float* be      = (const float*)d_in[17];
  const float* g_edge  = (const float*)d_in[18];
  const float* b_edge  = (const float*)d_in[19];
  const float* Wa      = (const float*)d_in[20];
  const float* ba      = (const float*)d_in[21];
  const float* W0      = (const float*)d_in[22];
  const float* b0      = (const float*)d_in[23];
  const float* Wc1     = (const float*)d_in[24];
  const float* Wc2     = (const float*)d_in[25];
  const int*   idx     = (const int*)d_in[26];
  const int*   topk    = (const int*)d_in[27];
  float* out = (float*)d_out;

  float* wsf = (float*)d_ws;
  float*    node  = wsf + WS_NODE;
  int*      cnt   = (int*)(wsf + WS_CNT);
  int*      jlist = (int*)(wsf + WS_JLIST);
  float*    m0bG  = wsf + WS_M0B;
  float*    partb = wsf + WS_PART;
  unsigned* packW = (unsigned*)(wsf + WS_PACKW);

  k_prep<<<512, 512, 0, stream>>>(msa, seq1hot, xyz, idx, topk, g_msa, b_msa,
                                  Wq, bq, Wk, bk, Wx, bx, g_node, b_node,
                                  We, Wa, W0, b0, Wc1, Wc2,
                                  node, cnt, jlist, m0bG, packW);
  k_main<<<512*SLI/4, 256, 0, stream>>>(pair, xyz, g_pair, b_pair, be, g_edge,
                                        b_edge, ba, node, cnt, jlist, m0bG,
                                        packW, partb);
  k_fin<<<512, 64, 0, stream>>>(xyz, cnt, partb, out);
}

// Round 20
// 37.456 us; speedup vs baseline: 1.1086x; 1.1086x over previous
//
#include <hip/hip_runtime.h>

#define EPSLN 1e-5f
#define KMINC 9
#define SLI   10         // slices per (b,i), 8 rows each -> covers n <= 80

typedef _Float16 h2 __attribute__((ext_vector_type(2)));
typedef _Float16 h4 __attribute__((ext_vector_type(4)));

#if defined(__has_builtin)
#if __has_builtin(__builtin_amdgcn_fdot2)
#define FDOT2(a,b,c) __builtin_amdgcn_fdot2((a),(b),(c),false)
#endif
#endif
#ifndef FDOT2
#define FDOT2(a,b,c) ((c) + (float)(a)[0]*(float)(b)[0] + (float)(a)[1]*(float)(b)[1])
#endif

__device__ __forceinline__ h2 mk2(float a, float b){
  h2 v; v[0]=(_Float16)a; v[1]=(_Float16)b; return v;
}
__device__ __forceinline__ unsigned h2bits(h2 v){
  union { h2 h; unsigned u; } c; c.h = v; return c.u;
}
__device__ __forceinline__ h2 asH2(unsigned u){
  union { unsigned u; h2 h; } c; c.u = u; return c.h;
}

// ---- DPP-based reductions (r17-verified): butterflies on the VALU pipe ----
template<int CTRL>
__device__ __forceinline__ float dppadd(float v){
  union { float f; int i; } a, r;
  a.f = v;
  r.i = __builtin_amdgcn_update_dpp(a.i, a.i, CTRL, 0xf, 0xf, true);
  return v + r.f;
}
__device__ __forceinline__ float wred16d(float v){
  v = dppadd<0x0B1>(v);
  v = dppadd<0x04E>(v);
  v = dppadd<0x124>(v);
  v = dppadd<0x128>(v);
  return v;
}
__device__ __forceinline__ float wred32(float v){
  v = wred16d(v);
  return v + __shfl_xor(v, 16, 64);
}
__device__ __forceinline__ float wred64(float v){
  v = wred16d(v);
  v += __shfl_xor(v, 16, 64);
  return v + __shfl_xor(v, 32, 64);
}

// ws word-offsets
#define WS_NODE   0
#define WS_CNT    16384
#define WS_JLIST  16896       // 512*96 ints
#define WS_M0B    66048       // 512*16 f32
#define WS_PART   74240       // 512*SLI*28 f32 = 143360
#define WS_PACKW  217600      // q-blocked packed weights (3552 u32)

// ---------------- Kernel P: msa-LN/attention/node + m0b + top-k mask + weight packing ----------------
// grid = B*L (512), block = 512 (8 waves). Phase-2 loads hoisted to kernel top (r20):
// D/sep/K computed before phase 1; Dv written early; barriers in phase 1 publish it.
__global__ __launch_bounds__(512) void k_prep(
    const float* __restrict__ msa, const float* __restrict__ seq1hot,
    const float* __restrict__ xyz, const int* __restrict__ idxp,
    const int* __restrict__ topk,
    const float* __restrict__ g_msa, const float* __restrict__ b_msa,
    const float* __restrict__ Wq, const float* __restrict__ bq,
    const float* __restrict__ Wk, const float* __restrict__ bk,
    const float* __restrict__ Wx, const float* __restrict__ bx,
    const float* __restrict__ g_node, const float* __restrict__ b_node,
    const float* __restrict__ We, const float* __restrict__ Wa,
    const float* __restrict__ W0, const float* __restrict__ b0,
    const float* __restrict__ Wc1, const float* __restrict__ Wc2,
    float* __restrict__ node, int* __restrict__ cnt, int* __restrict__ jlist,
    float* __restrict__ m0bG, unsigned* __restrict__ packW)
{
  const int bid = blockIdx.x;          // b*256 + l  (l == i)
  const int b = bid >> 8;
  const int tid = threadIdx.x;
  const int w = tid >> 6, lane = tid & 63;   // 8 waves

  __shared__ float mn[32][64];
  __shared__ float qS[64];
  __shared__ float scS[32];
  __shared__ float redS[8][64];
  __shared__ float ssumS[8];
  __shared__ float nodeS[32];
  __shared__ alignas(16) float Dv[256];
  __shared__ int   rankS[256];
  __shared__ int   wsum[4];

  // ---- r20: hoist phase-2 independent loads to the very top ----
  const bool act = tid < 256;
  const int i = bid & 255;
  const int j8 = tid & 255;
  int sepE = 0, KE = 64;
  if (act){
    const float cax = xyz[(bid*3+1)*3+0];
    const float cay = xyz[(bid*3+1)*3+1];
    const float caz = xyz[(bid*3+1)*3+2];
    const int jb = (b<<8)+j8;
    float dx = xyz[(jb*3+1)*3+0]-cax;
    float dy = xyz[(jb*3+1)*3+1]-cay;
    float dz = xyz[(jb*3+1)*3+2]-caz;
    Dv[j8] = sqrtf(dx*dx+dy*dy+dz*dz) + (i==j8 ? 999.9f : 0.f);
    sepE = abs(idxp[jb] - idxp[bid]);
    int K = topk[0];
    if (K<=0 || K>256){
      float f = ((const float*)topk)[0];
      K = (f>=1.f && f<=256.f) ? (int)f : 64;
    }
    KE = K;
  }

  // ---- block 0 packs weights q-blocked f16 into ws (for k_main) ----
  if (bid==0){
    for (int i2=tid;i2<2048;i2+=512){
      int qb=i2>>7, r7=i2&127, t=r7>>2, ii=r7&3, q=4*qb+ii;
      packW[i2] = h2bits(mk2(We[(2*q)*32+t], We[(2*q+1)*32+t]));
    }
    for (int i2=tid;i2<512; i2+=512){
      int qb=i2>>7, r7=i2&127, t=r7>>2, ii=r7&3, q=4*qb+ii;
      packW[2048+i2] = h2bits(mk2(Wa[(2*q)*32+t], Wa[(2*q+1)*32+t]));
    }
    for (int i2=tid;i2<768; i2+=512){
      int qb=i2>>6, r6=i2&63, tc=r6>>2, ii=r6&3, q=4*qb+ii;
      packW[2560+i2] = h2bits(mk2(W0[(2*q)*16+tc], W0[(2*q+1)*16+tc]));
    }
    if (tid<192){
      int qb=tid/48, r48=tid%48, tc=r48>>2, ii=r48&3, q=4*qb+ii;
      float lo = (tc<3)? Wc1[(2*q)*3+tc]   : Wc2[(2*q)*9+(tc-3)];
      float hi = (tc<3)? Wc1[(2*q+1)*3+tc] : Wc2[(2*q+1)*9+(tc-3)];
      packW[3328+tid] = h2bits(mk2(lo,hi));
    }
    if (tid<32) ((float*)packW)[3520+tid] = Wa[32*32+tid];
  }

  // ---- msa LN: wave w rows w, w+8, w+16, w+24 ----
  const float gm = g_msa[lane], bm = b_msa[lane];
  for (int nn=w; nn<32; nn+=8){
    float x = msa[(size_t)(((b*32+nn)<<8)+(bid&255))*64 + lane];
    float s = wred64(x), s2 = wred64(x*x);
    float mu = s*(1.f/64.f);
    float var = s2*(1.f/64.f) - mu*mu;
    mn[nn][lane] = (x-mu)*rsqrtf(var+EPSLN)*gm + bm;
  }
  __syncthreads();
  // ---- q[e=lane]: partial over d-range per wave ----
  {
    float p = (w==0)? bq[lane] : 0.f;
    for (int d=w*8; d<w*8+8; d++) p += mn[0][d]*Wq[d*64+lane];
    redS[w][lane] = p;
  }
  __syncthreads();
  if (w==0){
    float q = 0.f;
    #pragma unroll
    for (int k=0;k<8;k++) q += redS[k][lane];
    qS[lane] = q*0.125f;               // 1/sqrt(64)
  }
  __syncthreads();
  // ---- qk[d=lane]: partial over e-range per wave ----
  {
    float p = 0.f;
    for (int e=w*8; e<w*8+8; e++) p += Wk[lane*64+e]*qS[e];
    redS[w][lane] = p;
  }
  __syncthreads();
  float qk = 0.f;
  #pragma unroll
  for (int k=0;k<8;k++) qk += redS[k][lane];
  const float qb_ = wred64(qS[lane]*bk[lane]);
  // ---- scores: wave w rows w*4..w*4+3 ----
  for (int nn=w*4; nn<w*4+4; nn++){
    float p = wred64(mn[nn][lane]*qk);
    if (lane==0) scS[nn] = p + qb_;
  }
  __syncthreads();
  // ---- softmax + weighted msa ----
  float mx = -1e30f;
  for (int nn=0; nn<32; nn++) mx = fmaxf(mx, scS[nn]);
  float ps=0.f, pm=0.f;
  for (int nn=w*4; nn<w*4+4; nn++){
    float e = expf(scS[nn]-mx);
    ps += e; pm += e*mn[nn][lane];
  }
  redS[w][lane] = pm;
  if (lane==0) ssumS[w] = ps;
  __syncthreads();
  if (w==0){
    float ssum = 0.f, acc = 0.f;
    #pragma unroll
    for (int k=0;k<8;k++){ ssum += ssumS[k]; acc += redS[k][lane]; }
    qS[lane] = acc / ssum;
  }
  __syncthreads();
  if (tid<32){
    float acc = bx[tid];
    for (int k=0;k<64;k++) acc += qS[k]*Wx[k*32+tid];
    const float* s1 = &seq1hot[bid*21];
    for (int k=0;k<21;k++) acc += s1[k]*Wx[(64+k)*32+tid];
    float s = wred32(acc), s2 = wred32(acc*acc);
    float mu = s*(1.f/32.f), var = s2*(1.f/32.f)-mu*mu;
    float v = (acc-mu)*rsqrtf(var+EPSLN)*g_node[tid] + b_node[tid];
    node[bid*32+tid] = v;
    nodeS[tid] = v;
  }
  __syncthreads();
  if (tid<16){
    float acc = b0[tid];
    for (int k=0;k<32;k++) acc += nodeS[k]*W0[(32+k)*16+tid];
    m0bG[bid*16+tid] = acc;
  }
  __syncthreads();        // publish Dv (written at top) to all threads

  // --- Phase 2: split rank scan (both halves, race-free) + compaction ---
  int rankLo = 0;
  {
    const float Dj = Dv[j8];
    const int base = (tid >> 8) * 128;     // 0 for lower half, 128 for upper half
    int rank = 0;
    for (int j2=base; j2<base+128; j2+=4){
      const float4 dv = *(const float4*)&Dv[j2];
      rank += (dv.x < Dj || (dv.x == Dj && (j2+0) < j8)) ? 1 : 0;
      rank += (dv.y < Dj || (dv.y == Dj && (j2+1) < j8)) ? 1 : 0;
      rank += (dv.z < Dj || (dv.z == Dj && (j2+2) < j8)) ? 1 : 0;
      rank += (dv.w < Dj || (dv.w == Dj && (j2+3) < j8)) ? 1 : 0;
    }
    if (!act) rankS[j8] = rank;            // upper half deposits its partial
    else      rankLo = rank;               // lower half keeps it in register
  }
  __syncthreads();
  if (act){
    const int rank = rankLo + rankS[j8];
    const bool m = (rank < KE) || (i!=j8 && sepE < KMINC);
    unsigned long long bal = __ballot(m);
    const int l6 = j8 & 63, wv = j8 >> 6;
    const int pre = __popcll(bal & ((1ull<<l6)-1ull));
    if (l6==0) wsum[wv] = __popcll(bal);
    __syncthreads();
    int off = 0;
    for (int w2=0;w2<wv;w2++) off += wsum[w2];
    if (m) jlist[bid*96 + off + pre] = j8;
    if (j8==0) cnt[bid] = wsum[0]+wsum[1]+wsum[2]+wsum[3];
  } else {
    __syncthreads();
  }
}

// ---------------- Kernel C: wave-per-slice gathered pipeline, b128 LDS (r19-verified) ----------------
// grid = 512*SLI/4 (1280), block = 256 = 4 independent waves; wave = one 8-row slice.
// r20: cnt/jlist/pair-row gathers hoisted BEFORE the weight copy (latency hidden
// under ~40 global loads of the copy). jlist indices clamped &255: memory-safe;
// invalid-slot results discarded via vals gating at accumulation (unchanged semantics).
__global__ __launch_bounds__(256) void k_main(
    const float* __restrict__ pair, const float* __restrict__ xyz,
    const float* __restrict__ g_pair, const float* __restrict__ b_pair,
    const float* __restrict__ be, const float* __restrict__ g_edge,
    const float* __restrict__ b_edge, const float* __restrict__ ba,
    const float* __restrict__ node, const int* __restrict__ cnt,
    const int* __restrict__ jlist, const float* __restrict__ m0bG,
    const unsigned* __restrict__ packW, float* __restrict__ part)
{
  const int tid = threadIdx.x;
  const int w  = tid >> 6;          // wave 0..3
  const int wl = tid & 63;          // lane in wave
  const int r  = (tid >> 5) & 1;    // group in wave
  const int t  = tid & 31;          // lane in group

  __shared__ alignas(16) unsigned WeL[2048];        // 8 KB q-blocked
  __shared__ alignas(16) unsigned WaL[512];         // 2 KB
  __shared__ alignas(16) unsigned W0L[768];         // 3 KB
  __shared__ alignas(16) unsigned WcL[192];         // 768 B
  __shared__ float waD[32];
  __shared__ float beS[32], geS[32], beeS[32], baS[32];
  __shared__ alignas(16) _Float16 pnH[32][128];     // 8 KB
  __shared__ alignas(16) _Float16 edH[32][32];      // 2 KB
  __shared__ alignas(16) _Float16 aH [32][32];      // 2 KB
  __shared__ alignas(16) _Float16 ndH[32][32];      // 2 KB
  __shared__ float cS[32*12];
  __shared__ float xjS[32][9];
  __shared__ float geoS[32][4];

  const int s    = blockIdx.x*4 + w;   // slice id
  const int item = s / SLI;            // (b,i)
  const int sl   = s - item*SLI;
  const int b    = item >> 8;
  const int row0 = sl*8;
  const int wrow = w*8;

  // ---- r20: hoisted dependent-load chain (before weight copy) ----
  const int n = cnt[item];
  bool vals[4]; int jjs[4];
  float4 pvv[4]; float nvv[4];
  #pragma unroll
  for (int jc=0;jc<4;jc++){
    const int slot = row0 + r*4 + jc;
    vals[jc] = slot < n;
    jjs[jc] = jlist[item*96 + slot] & 255;     // memory-safe clamp; garbage gated later
  }
  #pragma unroll
  for (int jc=0;jc<4;jc++){
    pvv[jc] = *(const float4*)&pair[(((long)item*256 + jjs[jc])*128) + 4*t];
    nvv[jc] = node[((b<<8)+jjs[jc])*32 + t];
  }

  // ---- vectorized weight copy (uint4) — executes under the gather latency ----
  {
    const uint4* p4 = (const uint4*)packW;
    #pragma unroll
    for (int i2=tid;i2<512;i2+=256) ((uint4*)WeL)[i2] = p4[i2];
    if (tid<128) ((uint4*)WaL)[tid] = p4[512+tid];
    if (tid<192) ((uint4*)W0L)[tid] = p4[640+tid];
    if (tid<48)  ((uint4*)WcL)[tid] = p4[832+tid];
  }
  if (tid<32){
    waD[tid] = ((const float*)packW)[3520+tid];
    beS[tid]=be[tid]; geS[tid]=g_edge[tid]; beeS[tid]=b_edge[tid]; baS[tid]=ba[tid];
  }
  __syncthreads();        // the ONLY block-wide barrier

  float stA = 0.f;
  float ofA = 0.f;

  if (row0 < n){
    const float cax = xyz[(item*3+1)*3+0];
    const float cay = xyz[(item*3+1)*3+1];
    const float caz = xyz[(item*3+1)*3+2];
    // ---- stage 4 rows per group (from preloaded registers) ----
    {
      const float4 gp4 = *(const float4*)&g_pair[4*t];
      const float4 bp4 = *(const float4*)&b_pair[4*t];
      #pragma unroll
      for (int jc=0;jc<4;jc++){
        const int row = wrow + r*4 + jc;
        const float4 pv4 = pvv[jc];
        float sm  = wred32(pv4.x+pv4.y+pv4.z+pv4.w);
        float sm2 = wred32(pv4.x*pv4.x+pv4.y*pv4.y+pv4.z*pv4.z+pv4.w*pv4.w);
        float mu = sm*(1.f/128.f);
        float var = sm2*(1.f/128.f)-mu*mu;
        float rs = rsqrtf(var+EPSLN);
        h4 o;
        o[0]=(_Float16)((pv4.x-mu)*rs*gp4.x+bp4.x);
        o[1]=(_Float16)((pv4.y-mu)*rs*gp4.y+bp4.y);
        o[2]=(_Float16)((pv4.z-mu)*rs*gp4.z+bp4.z);
        o[3]=(_Float16)((pv4.w-mu)*rs*gp4.w+bp4.w);
        *(h4*)&pnH[row][4*t] = o;
        const int jb=(b<<8)+jjs[jc];
        ndH[row][t] = (_Float16)nvv[jc];
        if (t<9) xjS[row][t] = xyz[(size_t)jb*9 + t];
        if (t==0){
          float jx = xyz[(size_t)jb*9+3]-cax;
          float jy = xyz[(size_t)jb*9+4]-cay;
          float jz = xyz[(size_t)jb*9+5]-caz;
          geoS[row][0]=jx; geoS[row][1]=jy; geoS[row][2]=jz;
          geoS[row][3]=sqrtf(jx*jx+jy*jy+jz*jz);
        }
      }
    }
    // ---- edge GEMV (128->32): 16 iters, all-b128 ----
    float ea0[4], ea1[4];
    #pragma unroll
    for (int jc=0;jc<4;jc++){ ea0[jc]=beS[t]; ea1[jc]=0.f; }
    for (int qb=0; qb<16; ++qb){
      const uint4 wv = *(const uint4*)&WeL[qb*128 + t*4];
      #pragma unroll
      for (int jc=0;jc<4;jc++){
        const uint4 pv = *(const uint4*)&pnH[wrow + r*4 + jc][8*qb];
        ea0[jc]=FDOT2(asH2(wv.y), asH2(pv.y), FDOT2(asH2(wv.x), asH2(pv.x), ea0[jc]));
        ea1[jc]=FDOT2(asH2(wv.w), asH2(pv.w), FDOT2(asH2(wv.z), asH2(pv.z), ea1[jc]));
      }
    }
    // ---- edge LN -> edH f16 ----
    #pragma unroll
    for (int jc=0;jc<4;jc++){
      float acc=ea0[jc]+ea1[jc];
      float sm=wred32(acc), sm2=wred32(acc*acc);
      float mu=sm*(1.f/32.f), var=sm2*(1.f/32.f)-mu*mu;
      edH[wrow + r*4 + jc][t] = (_Float16)((acc-mu)*rsqrtf(var+EPSLN)*geS[t]+beeS[t]);
    }
    // ---- a = relu([edge, dist] @ Wa + ba) ----
    float av[4];
    #pragma unroll
    for (int jc=0;jc<4;jc++) av[jc]=baS[t]+geoS[wrow + r*4 + jc][3]*waD[t];
    for (int qb=0; qb<4; ++qb){
      const uint4 wv = *(const uint4*)&WaL[qb*128 + t*4];
      #pragma unroll
      for (int jc=0;jc<4;jc++){
        const uint4 ev = *(const uint4*)&edH[wrow + r*4 + jc][8*qb];
        av[jc]=FDOT2(asH2(wv.w), asH2(ev.w), FDOT2(asH2(wv.z), asH2(ev.z),
                FDOT2(asH2(wv.y), asH2(ev.y), FDOT2(asH2(wv.x), asH2(ev.x), av[jc]))));
      }
    }
    #pragma unroll
    for (int jc=0;jc<4;jc++) aH[wrow + r*4 + jc][t]=(_Float16)fmaxf(av[jc],0.f);
    // ---- m0: a-part lanes t<16 (W0 blocks 0..3), node-part t>=16 (blocks 8..11) ----
    {
      const int half = t>>4, tc = t&15;
      const int wb = half ? 8 : 0;
      const float m0b = half ? 0.f : m0bG[item*16+tc];
      float m0v[4];
      #pragma unroll
      for (int jc=0;jc<4;jc++) m0v[jc]=m0b;
      for (int qb=0;qb<4;++qb){
        const uint4 wv = *(const uint4*)&W0L[(wb+qb)*64 + tc*4];
        #pragma unroll
        for (int jc=0;jc<4;jc++){
          const _Float16* opb = half ? &ndH[wrow + r*4 + jc][0] : &aH[wrow + r*4 + jc][0];
          const uint4 ov = *(const uint4*)&opb[8*qb];
          m0v[jc]=FDOT2(asH2(wv.w), asH2(ov.w), FDOT2(asH2(wv.z), asH2(ov.z),
                   FDOT2(asH2(wv.y), asH2(ov.y), FDOT2(asH2(wv.x), asH2(ov.x), m0v[jc]))));
        }
      }
      #pragma unroll
      for (int jc=0;jc<4;jc++){
        float tot = m0v[jc] + __shfl_xor(m0v[jc], 16);
        if (t<16 && vals[jc]) stA += fmaxf(tot, 0.f);
      }
    }
    // ---- c1/c2 from a: lanes t<12 k-rows 0..15 (blocks 0..1), lanes 12..23 k 16..31 (blocks 2..3) ----
    {
      const bool up = (t>=12 && t<24);
      const int tc12 = up ? t-12 : (t<12 ? t : 0);
      const int wb = up ? 2 : 0;
      const int koff = up ? 16 : 0;
      float cv[4]={0.f,0.f,0.f,0.f};
      for (int qb=0;qb<2;++qb){
        const uint4 wv = *(const uint4*)&WcL[(wb+qb)*48 + tc12*4];
        #pragma unroll
        for (int jc=0;jc<4;jc++){
          const uint4 av2 = *(const uint4*)&aH[wrow + r*4 + jc][koff + 8*qb];
          cv[jc]=FDOT2(asH2(wv.w), asH2(av2.w), FDOT2(asH2(wv.z), asH2(av2.z),
                  FDOT2(asH2(wv.y), asH2(av2.y), FDOT2(asH2(wv.x), asH2(av2.x), cv[jc]))));
        }
      }
      #pragma unroll
      for (int jc=0;jc<4;jc++){
        const int src = (t<12) ? t+12 : (up ? t-12 : t);
        float other = __shfl(cv[jc], src, 32);
        if (t<12) cS[(wrow + r*4 + jc)*12+t] = cv[jc]+other;
      }
    }
    // ---- offset accumulation (t<9) ----
    if (t<9){
      const int o=t/3, x=t-o*3;
      #pragma unroll
      for (int jc=0;jc<4;jc++){
        if (!vals[jc]) continue;
        const int row = wrow + r*4 + jc;
        const float dj = geoS[row][3];
        const float dh = geoS[row][x]/(dj+1e-8f);
        const float* cr = &cS[row*12];
        float val = cr[o]*dh;
        const float caxj = xjS[row][3+x];
        #pragma unroll
        for (int c=0;c<3;c++){
          val += cr[3+o*3+c]*(xjS[row][c*3+x]-caxj);
        }
        ofA += val;
      }
    }
  }

  stA += __shfl_xor(stA, 32);
  ofA += __shfl_xor(ofA, 32);
  if (wl < 16) part[s*28 + wl] = stA;
  if (wl < 9)  part[s*28 + 16 + wl] = ofA;
}

// ---------------- Kernel F: combine partials, scale by deg, form xyz_new ----------------
// grid = B*L (512), block = 64
__global__ __launch_bounds__(64) void k_fin(
    const float* __restrict__ xyz, const int* __restrict__ cnt,
    const float* __restrict__ part, float* __restrict__ out)
{
  const int bid = blockIdx.x;
  const int t = threadIdx.x;
  __shared__ float offF[9];
  const int n = cnt[bid];
  const float invd = 1.f/fmaxf((float)n,1.f);
  if (t<16){
    float s=0.f;
    #pragma unroll
    for (int k2=0;k2<SLI;k2++) s += part[(bid*SLI+k2)*28 + t];
    out[4608 + bid*16 + t] = s*invd;           // state
  } else if (t<25){
    float s=0.f;
    #pragma unroll
    for (int k2=0;k2<SLI;k2++) s += part[(bid*SLI+k2)*28 + t];
    offF[t-16] = s*invd;
  }
  __syncthreads();
  if (t<9){
    const int o=t/3, x=t-o*3;
    const float cac = xyz[(bid*3+1)*3+x];
    const float CA = cac + offF[3+x];          // offset[:,:,1]
    const float v = (o==1)? CA : (CA + offF[o*3+x]);
    out[bid*9 + t] = v;                        // xyz_new
  }
}

extern "C" void kernel_launch(void* const* d_in, const int* in_sizes, int n_in,
                              void* d_out, int out_size, void* d_ws, size_t ws_size,
                              hipStream_t stream)
{
  const float* msa     = (const float*)d_in[0];
  const float* pair    = (const float*)d_in[1];
  const float* xyz     = (const float*)d_in[2];
  const float* seq1hot = (const float*)d_in[3];
  const float* g_msa   = (const float*)d_in[4];
  const float* b_msa   = (const float*)d_in[5];
  const float* g_pair  = (const float*)d_in[6];
  const float* b_pair  = (const float*)d_in[7];
  const float* Wq      = (const float*)d_in[8];
  const float* bq      = (const float*)d_in[9];
  const float* Wk      = (const float*)d_in[10];
  const float* bk      = (const float*)d_in[11];
  const float* Wx      = (const float*)d_in[12];
  const float* bx      = (const float*)d_in[13];
  const float* g_node  = (const float*)d_in[14];
  const float* b_node  = (const float*)d_in[15];
  const float* We      = (const float*)d_in[16];
  const float* be      = (const float*)d_in[17];
  const float* g_edge  = (const float*)d_in[18];
  const float* b_edge  = (const float*)d_in[19];
  const float* Wa      = (const float*)d_in[20];
  const float* ba      = (const float*)d_in[21];
  const float* W0      = (const float*)d_in[22];
  const float* b0      = (const float*)d_in[23];
  const float* Wc1     = (const float*)d_in[24];
  const float* Wc2     = (const float*)d_in[25];
  const int*   idx     = (const int*)d_in[26];
  const int*   topk    = (const int*)d_in[27];
  float* out = (float*)d_out;

  float* wsf = (float*)d_ws;
  float*    node  = wsf + WS_NODE;
  int*      cnt   = (int*)(wsf + WS_CNT);
  int*      jlist = (int*)(wsf + WS_JLIST);
  float*    m0bG  = wsf + WS_M0B;
  float*    partb = wsf + WS_PART;
  unsigned* packW = (unsigned*)(wsf + WS_PACKW);

  k_prep<<<512, 512, 0, stream>>>(msa, seq1hot, xyz, idx, topk, g_msa, b_msa,
                                  Wq, bq, Wk, bk, Wx, bx, g_node, b_node,
                                  We, Wa, W0, b0, Wc1, Wc2,
                                  node, cnt, jlist, m0bG, packW);
  k_main<<<512*SLI/4, 256, 0, stream>>>(pair, xyz, g_pair, b_pair, be, g_edge,
                                        b_edge, ba, node, cnt, jlist, m0bG,
                                        packW, partb);
  k_fin<<<512, 64, 0, stream>>>(xyz, cnt, partb, out);
}

// Round 21
// 37.222 us; speedup vs baseline: 1.1156x; 1.0063x over previous
//
#include <hip/hip_runtime.h>

#define EPSLN 1e-5f
#define KMINC 9
#define SLI   10         // slices per (b,i), 8 rows each -> covers n <= 80

typedef _Float16 h2 __attribute__((ext_vector_type(2)));
typedef _Float16 h4 __attribute__((ext_vector_type(4)));

#if defined(__has_builtin)
#if __has_builtin(__builtin_amdgcn_fdot2)
#define FDOT2(a,b,c) __builtin_amdgcn_fdot2((a),(b),(c),false)
#endif
#endif
#ifndef FDOT2
#define FDOT2(a,b,c) ((c) + (float)(a)[0]*(float)(b)[0] + (float)(a)[1]*(float)(b)[1])
#endif

__device__ __forceinline__ h2 mk2(float a, float b){
  h2 v; v[0]=(_Float16)a; v[1]=(_Float16)b; return v;
}
__device__ __forceinline__ unsigned h2bits(h2 v){
  union { h2 h; unsigned u; } c; c.h = v; return c.u;
}
__device__ __forceinline__ h2 asH2(unsigned u){
  union { unsigned u; h2 h; } c; c.u = u; return c.h;
}

// ---- DPP-based reductions (r17-verified): butterflies on the VALU pipe ----
template<int CTRL>
__device__ __forceinline__ float dppadd(float v){
  union { float f; int i; } a, r;
  a.f = v;
  r.i = __builtin_amdgcn_update_dpp(a.i, a.i, CTRL, 0xf, 0xf, true);
  return v + r.f;
}
__device__ __forceinline__ float wred16d(float v){
  v = dppadd<0x0B1>(v);
  v = dppadd<0x04E>(v);
  v = dppadd<0x124>(v);
  v = dppadd<0x128>(v);
  return v;
}
__device__ __forceinline__ float wred32(float v){
  v = wred16d(v);
  return v + __shfl_xor(v, 16, 64);
}
__device__ __forceinline__ float wred64(float v){
  v = wred16d(v);
  v += __shfl_xor(v, 16, 64);
  return v + __shfl_xor(v, 32, 64);
}

// ws word-offsets
#define WS_NODE   0
#define WS_CNT    16384
#define WS_JLIST  16896       // 512*96 ints
#define WS_M0B    66048       // 512*16 f32
#define WS_PART   74240       // 512*SLI*28 f32 = 143360
#define WS_PACKW  217600      // q-blocked packed weights (3552 u32)

// ---------------- Kernel P: msa-LN/attention/node + m0b + top-k mask + weight packing ----------------
// grid = B*L (512), block = 512 (8 waves). r20: phase-2 loads hoisted to top.
// r21: msa rows + Wq/Wk weights preloaded into registers at kernel top, so the
// barrier-to-barrier phases contain no global-latency heads.
__global__ __launch_bounds__(512) void k_prep(
    const float* __restrict__ msa, const float* __restrict__ seq1hot,
    const float* __restrict__ xyz, const int* __restrict__ idxp,
    const int* __restrict__ topk,
    const float* __restrict__ g_msa, const float* __restrict__ b_msa,
    const float* __restrict__ Wq, const float* __restrict__ bq,
    const float* __restrict__ Wk, const float* __restrict__ bk,
    const float* __restrict__ Wx, const float* __restrict__ bx,
    const float* __restrict__ g_node, const float* __restrict__ b_node,
    const float* __restrict__ We, const float* __restrict__ Wa,
    const float* __restrict__ W0, const float* __restrict__ b0,
    const float* __restrict__ Wc1, const float* __restrict__ Wc2,
    float* __restrict__ node, int* __restrict__ cnt, int* __restrict__ jlist,
    float* __restrict__ m0bG, unsigned* __restrict__ packW)
{
  const int bid = blockIdx.x;          // b*256 + l  (l == i)
  const int b = bid >> 8;
  const int tid = threadIdx.x;
  const int w = tid >> 6, lane = tid & 63;   // 8 waves

  __shared__ float mn[32][64];
  __shared__ float qS[64];
  __shared__ float scS[32];
  __shared__ float redS[8][64];
  __shared__ float ssumS[8];
  __shared__ float nodeS[32];
  __shared__ alignas(16) float Dv[256];
  __shared__ int   rankS[256];
  __shared__ int   wsum[4];

  // ---- r20/r21: hoist ALL independent global loads to the very top ----
  const bool act = tid < 256;
  const int i = bid & 255;
  const int j8 = tid & 255;
  int sepE = 0, KE = 64;
  if (act){
    const float cax = xyz[(bid*3+1)*3+0];
    const float cay = xyz[(bid*3+1)*3+1];
    const float caz = xyz[(bid*3+1)*3+2];
    const int jb = (b<<8)+j8;
    float dx = xyz[(jb*3+1)*3+0]-cax;
    float dy = xyz[(jb*3+1)*3+1]-cay;
    float dz = xyz[(jb*3+1)*3+2]-caz;
    Dv[j8] = sqrtf(dx*dx+dy*dy+dz*dz) + (i==j8 ? 999.9f : 0.f);
    sepE = abs(idxp[jb] - idxp[bid]);
    int K = topk[0];
    if (K<=0 || K>256){
      float f = ((const float*)topk)[0];
      K = (f>=1.f && f<=256.f) ? (int)f : 64;
    }
    KE = K;
  }
  // r21: msa rows for this wave (loads issue here; reductions later)
  float msav[4];
  #pragma unroll
  for (int k=0;k<4;k++)
    msav[k] = msa[(size_t)(((b*32+(w+8*k))<<8)+(bid&255))*64 + lane];
  // r21: Wq/Wk slices for this wave's q/qk partials
  float wqv[8], wkv[8];
  #pragma unroll
  for (int d=0;d<8;d++){
    wqv[d] = Wq[(w*8+d)*64 + lane];
    wkv[d] = Wk[lane*64 + (w*8+d)];
  }

  // ---- block 0 packs weights q-blocked f16 into ws (for k_main) ----
  if (bid==0){
    for (int i2=tid;i2<2048;i2+=512){
      int qb=i2>>7, r7=i2&127, t=r7>>2, ii=r7&3, q=4*qb+ii;
      packW[i2] = h2bits(mk2(We[(2*q)*32+t], We[(2*q+1)*32+t]));
    }
    for (int i2=tid;i2<512; i2+=512){
      int qb=i2>>7, r7=i2&127, t=r7>>2, ii=r7&3, q=4*qb+ii;
      packW[2048+i2] = h2bits(mk2(Wa[(2*q)*32+t], Wa[(2*q+1)*32+t]));
    }
    for (int i2=tid;i2<768; i2+=512){
      int qb=i2>>6, r6=i2&63, tc=r6>>2, ii=r6&3, q=4*qb+ii;
      packW[2560+i2] = h2bits(mk2(W0[(2*q)*16+tc], W0[(2*q+1)*16+tc]));
    }
    if (tid<192){
      int qb=tid/48, r48=tid%48, tc=r48>>2, ii=r48&3, q=4*qb+ii;
      float lo = (tc<3)? Wc1[(2*q)*3+tc]   : Wc2[(2*q)*9+(tc-3)];
      float hi = (tc<3)? Wc1[(2*q+1)*3+tc] : Wc2[(2*q+1)*9+(tc-3)];
      packW[3328+tid] = h2bits(mk2(lo,hi));
    }
    if (tid<32) ((float*)packW)[3520+tid] = Wa[32*32+tid];
  }

  // ---- msa LN: wave w rows w, w+8, w+16, w+24 (from preloaded registers) ----
  const float gm = g_msa[lane], bm = b_msa[lane];
  #pragma unroll
  for (int k=0;k<4;k++){
    const int nn = w + 8*k;
    float x = msav[k];
    float s = wred64(x), s2 = wred64(x*x);
    float mu = s*(1.f/64.f);
    float var = s2*(1.f/64.f) - mu*mu;
    mn[nn][lane] = (x-mu)*rsqrtf(var+EPSLN)*gm + bm;
  }
  __syncthreads();
  // ---- q[e=lane]: partial over d-range per wave (weights preloaded) ----
  {
    float p = (w==0)? bq[lane] : 0.f;
    #pragma unroll
    for (int d=0;d<8;d++) p += mn[0][w*8+d]*wqv[d];
    redS[w][lane] = p;
  }
  __syncthreads();
  if (w==0){
    float q = 0.f;
    #pragma unroll
    for (int k=0;k<8;k++) q += redS[k][lane];
    qS[lane] = q*0.125f;               // 1/sqrt(64)
  }
  __syncthreads();
  // ---- qk[d=lane]: partial over e-range per wave (weights preloaded) ----
  {
    float p = 0.f;
    #pragma unroll
    for (int e=0;e<8;e++) p += wkv[e]*qS[w*8+e];
    redS[w][lane] = p;
  }
  __syncthreads();
  float qk = 0.f;
  #pragma unroll
  for (int k=0;k<8;k++) qk += redS[k][lane];
  const float qb_ = wred64(qS[lane]*bk[lane]);
  // ---- scores: wave w rows w*4..w*4+3 ----
  for (int nn=w*4; nn<w*4+4; nn++){
    float p = wred64(mn[nn][lane]*qk);
    if (lane==0) scS[nn] = p + qb_;
  }
  __syncthreads();
  // ---- softmax + weighted msa ----
  float mx = -1e30f;
  for (int nn=0; nn<32; nn++) mx = fmaxf(mx, scS[nn]);
  float ps=0.f, pm=0.f;
  for (int nn=w*4; nn<w*4+4; nn++){
    float e = expf(scS[nn]-mx);
    ps += e; pm += e*mn[nn][lane];
  }
  redS[w][lane] = pm;
  if (lane==0) ssumS[w] = ps;
  __syncthreads();
  if (w==0){
    float ssum = 0.f, acc = 0.f;
    #pragma unroll
    for (int k=0;k<8;k++){ ssum += ssumS[k]; acc += redS[k][lane]; }
    qS[lane] = acc / ssum;
  }
  __syncthreads();
  if (tid<32){
    float acc = bx[tid];
    for (int k=0;k<64;k++) acc += qS[k]*Wx[k*32+tid];
    const float* s1 = &seq1hot[bid*21];
    for (int k=0;k<21;k++) acc += s1[k]*Wx[(64+k)*32+tid];
    float s = wred32(acc), s2 = wred32(acc*acc);
    float mu = s*(1.f/32.f), var = s2*(1.f/32.f)-mu*mu;
    float v = (acc-mu)*rsqrtf(var+EPSLN)*g_node[tid] + b_node[tid];
    node[bid*32+tid] = v;
    nodeS[tid] = v;
  }
  __syncthreads();
  if (tid<16){
    float acc = b0[tid];
    for (int k=0;k<32;k++) acc += nodeS[k]*W0[(32+k)*16+tid];
    m0bG[bid*16+tid] = acc;
  }
  __syncthreads();        // publish Dv (written at top) to all threads

  // --- Phase 2: split rank scan (both halves, race-free) + compaction ---
  int rankLo = 0;
  {
    const float Dj = Dv[j8];
    const int base = (tid >> 8) * 128;     // 0 for lower half, 128 for upper half
    int rank = 0;
    for (int j2=base; j2<base+128; j2+=4){
      const float4 dv = *(const float4*)&Dv[j2];
      rank += (dv.x < Dj || (dv.x == Dj && (j2+0) < j8)) ? 1 : 0;
      rank += (dv.y < Dj || (dv.y == Dj && (j2+1) < j8)) ? 1 : 0;
      rank += (dv.z < Dj || (dv.z == Dj && (j2+2) < j8)) ? 1 : 0;
      rank += (dv.w < Dj || (dv.w == Dj && (j2+3) < j8)) ? 1 : 0;
    }
    if (!act) rankS[j8] = rank;            // upper half deposits its partial
    else      rankLo = rank;               // lower half keeps it in register
  }
  __syncthreads();
  if (act){
    const int rank = rankLo + rankS[j8];
    const bool m = (rank < KE) || (i!=j8 && sepE < KMINC);
    unsigned long long bal = __ballot(m);
    const int l6 = j8 & 63, wv = j8 >> 6;
    const int pre = __popcll(bal & ((1ull<<l6)-1ull));
    if (l6==0) wsum[wv] = __popcll(bal);
    __syncthreads();
    int off = 0;
    for (int w2=0;w2<wv;w2++) off += wsum[w2];
    if (m) jlist[bid*96 + off + pre] = j8;
    if (j8==0) cnt[bid] = wsum[0]+wsum[1]+wsum[2]+wsum[3];
  } else {
    __syncthreads();
  }
}

// ---------------- Kernel C: wave-per-slice gathered pipeline, b128 LDS (r20-verified) ----------------
// grid = 512*SLI/4 (1280), block = 256 = 4 independent waves; wave = one 8-row slice.
// r20: cnt/jlist/pair/node gathers hoisted before weight copy. r21: xyz gathers
// (xjS rows + t==0 geometry trio + CA_i) hoisted into the same pre-barrier phase.
__global__ __launch_bounds__(256) void k_main(
    const float* __restrict__ pair, const float* __restrict__ xyz,
    const float* __restrict__ g_pair, const float* __restrict__ b_pair,
    const float* __restrict__ be, const float* __restrict__ g_edge,
    const float* __restrict__ b_edge, const float* __restrict__ ba,
    const float* __restrict__ node, const int* __restrict__ cnt,
    const int* __restrict__ jlist, const float* __restrict__ m0bG,
    const unsigned* __restrict__ packW, float* __restrict__ part)
{
  const int tid = threadIdx.x;
  const int w  = tid >> 6;          // wave 0..3
  const int wl = tid & 63;          // lane in wave
  const int r  = (tid >> 5) & 1;    // group in wave
  const int t  = tid & 31;          // lane in group

  __shared__ alignas(16) unsigned WeL[2048];        // 8 KB q-blocked
  __shared__ alignas(16) unsigned WaL[512];         // 2 KB
  __shared__ alignas(16) unsigned W0L[768];         // 3 KB
  __shared__ alignas(16) unsigned WcL[192];         // 768 B
  __shared__ float waD[32];
  __shared__ float beS[32], geS[32], beeS[32], baS[32];
  __shared__ alignas(16) _Float16 pnH[32][128];     // 8 KB
  __shared__ alignas(16) _Float16 edH[32][32];      // 2 KB
  __shared__ alignas(16) _Float16 aH [32][32];      // 2 KB
  __shared__ alignas(16) _Float16 ndH[32][32];      // 2 KB
  __shared__ float cS[32*12];
  __shared__ float xjS[32][9];
  __shared__ float geoS[32][4];

  const int s    = blockIdx.x*4 + w;   // slice id
  const int item = s / SLI;            // (b,i)
  const int sl   = s - item*SLI;
  const int b    = item >> 8;
  const int row0 = sl*8;
  const int wrow = w*8;

  // ---- r20/r21: hoisted dependent-load chain (before weight copy) ----
  const int n = cnt[item];
  const float cax = xyz[(item*3+1)*3+0];
  const float cay = xyz[(item*3+1)*3+1];
  const float caz = xyz[(item*3+1)*3+2];
  bool vals[4]; int jjs[4];
  float4 pvv[4]; float nvv[4]; float xjv[4];
  float gxa[4], gya[4], gza[4];
  #pragma unroll
  for (int jc=0;jc<4;jc++){
    const int slot = row0 + r*4 + jc;
    vals[jc] = slot < n;
    jjs[jc] = jlist[item*96 + slot] & 255;     // memory-safe clamp; garbage gated later
  }
  #pragma unroll
  for (int jc=0;jc<4;jc++){
    const int jb = (b<<8)+jjs[jc];
    pvv[jc] = *(const float4*)&pair[(((long)item*256 + jjs[jc])*128) + 4*t];
    nvv[jc] = node[jb*32 + t];
    xjv[jc] = (t<9) ? xyz[(size_t)jb*9 + t] : 0.f;
    gxa[jc]=0.f; gya[jc]=0.f; gza[jc]=0.f;
    if (t==0){
      gxa[jc] = xyz[(size_t)jb*9+3];
      gya[jc] = xyz[(size_t)jb*9+4];
      gza[jc] = xyz[(size_t)jb*9+5];
    }
  }

  // ---- vectorized weight copy (uint4) — executes under the gather latency ----
  {
    const uint4* p4 = (const uint4*)packW;
    #pragma unroll
    for (int i2=tid;i2<512;i2+=256) ((uint4*)WeL)[i2] = p4[i2];
    if (tid<128) ((uint4*)WaL)[tid] = p4[512+tid];
    if (tid<192) ((uint4*)W0L)[tid] = p4[640+tid];
    if (tid<48)  ((uint4*)WcL)[tid] = p4[832+tid];
  }
  if (tid<32){
    waD[tid] = ((const float*)packW)[3520+tid];
    beS[tid]=be[tid]; geS[tid]=g_edge[tid]; beeS[tid]=b_edge[tid]; baS[tid]=ba[tid];
  }
  __syncthreads();        // the ONLY block-wide barrier

  float stA = 0.f;
  float ofA = 0.f;

  if (row0 < n){
    // ---- stage 4 rows per group (from preloaded registers) ----
    {
      const float4 gp4 = *(const float4*)&g_pair[4*t];
      const float4 bp4 = *(const float4*)&b_pair[4*t];
      #pragma unroll
      for (int jc=0;jc<4;jc++){
        const int row = wrow + r*4 + jc;
        const float4 pv4 = pvv[jc];
        float sm  = wred32(pv4.x+pv4.y+pv4.z+pv4.w);
        float sm2 = wred32(pv4.x*pv4.x+pv4.y*pv4.y+pv4.z*pv4.z+pv4.w*pv4.w);
        float mu = sm*(1.f/128.f);
        float var = sm2*(1.f/128.f)-mu*mu;
        float rs = rsqrtf(var+EPSLN);
        h4 o;
        o[0]=(_Float16)((pv4.x-mu)*rs*gp4.x+bp4.x);
        o[1]=(_Float16)((pv4.y-mu)*rs*gp4.y+bp4.y);
        o[2]=(_Float16)((pv4.z-mu)*rs*gp4.z+bp4.z);
        o[3]=(_Float16)((pv4.w-mu)*rs*gp4.w+bp4.w);
        *(h4*)&pnH[row][4*t] = o;
        ndH[row][t] = (_Float16)nvv[jc];
        if (t<9) xjS[row][t] = xjv[jc];
        if (t==0){
          float jx = gxa[jc]-cax;
          float jy = gya[jc]-cay;
          float jz = gza[jc]-caz;
          geoS[row][0]=jx; geoS[row][1]=jy; geoS[row][2]=jz;
          geoS[row][3]=sqrtf(jx*jx+jy*jy+jz*jz);
        }
      }
    }
    // ---- edge GEMV (128->32): 16 iters, all-b128 ----
    float ea0[4], ea1[4];
    #pragma unroll
    for (int jc=0;jc<4;jc++){ ea0[jc]=beS[t]; ea1[jc]=0.f; }
    for (int qb=0; qb<16; ++qb){
      const uint4 wv = *(const uint4*)&WeL[qb*128 + t*4];
      #pragma unroll
      for (int jc=0;jc<4;jc++){
        const uint4 pv = *(const uint4*)&pnH[wrow + r*4 + jc][8*qb];
        ea0[jc]=FDOT2(asH2(wv.y), asH2(pv.y), FDOT2(asH2(wv.x), asH2(pv.x), ea0[jc]));
        ea1[jc]=FDOT2(asH2(wv.w), asH2(pv.w), FDOT2(asH2(wv.z), asH2(pv.z), ea1[jc]));
      }
    }
    // ---- edge LN -> edH f16 ----
    #pragma unroll
    for (int jc=0;jc<4;jc++){
      float acc=ea0[jc]+ea1[jc];
      float sm=wred32(acc), sm2=wred32(acc*acc);
      float mu=sm*(1.f/32.f), var=sm2*(1.f/32.f)-mu*mu;
      edH[wrow + r*4 + jc][t] = (_Float16)((acc-mu)*rsqrtf(var+EPSLN)*geS[t]+beeS[t]);
    }
    // ---- a = relu([edge, dist] @ Wa + ba) ----
    float av[4];
    #pragma unroll
    for (int jc=0;jc<4;jc++) av[jc]=baS[t]+geoS[wrow + r*4 + jc][3]*waD[t];
    for (int qb=0; qb<4; ++qb){
      const uint4 wv = *(const uint4*)&WaL[qb*128 + t*4];
      #pragma unroll
      for (int jc=0;jc<4;jc++){
        const uint4 ev = *(const uint4*)&edH[wrow + r*4 + jc][8*qb];
        av[jc]=FDOT2(asH2(wv.w), asH2(ev.w), FDOT2(asH2(wv.z), asH2(ev.z),
                FDOT2(asH2(wv.y), asH2(ev.y), FDOT2(asH2(wv.x), asH2(ev.x), av[jc]))));
      }
    }
    #pragma unroll
    for (int jc=0;jc<4;jc++) aH[wrow + r*4 + jc][t]=(_Float16)fmaxf(av[jc],0.f);
    // ---- m0: a-part lanes t<16 (W0 blocks 0..3), node-part t>=16 (blocks 8..11) ----
    {
      const int half = t>>4, tc = t&15;
      const int wb = half ? 8 : 0;
      const float m0b = half ? 0.f : m0bG[item*16+tc];
      float m0v[4];
      #pragma unroll
      for (int jc=0;jc<4;jc++) m0v[jc]=m0b;
      for (int qb=0;qb<4;++qb){
        const uint4 wv = *(const uint4*)&W0L[(wb+qb)*64 + tc*4];
        #pragma unroll
        for (int jc=0;jc<4;jc++){
          const _Float16* opb = half ? &ndH[wrow + r*4 + jc][0] : &aH[wrow + r*4 + jc][0];
          const uint4 ov = *(const uint4*)&opb[8*qb];
          m0v[jc]=FDOT2(asH2(wv.w), asH2(ov.w), FDOT2(asH2(wv.z), asH2(ov.z),
                   FDOT2(asH2(wv.y), asH2(ov.y), FDOT2(asH2(wv.x), asH2(ov.x), m0v[jc]))));
        }
      }
      #pragma unroll
      for (int jc=0;jc<4;jc++){
        float tot = m0v[jc] + __shfl_xor(m0v[jc], 16);
        if (t<16 && vals[jc]) stA += fmaxf(tot, 0.f);
      }
    }
    // ---- c1/c2 from a: lanes t<12 k-rows 0..15 (blocks 0..1), lanes 12..23 k 16..31 (blocks 2..3) ----
    {
      const bool up = (t>=12 && t<24);
      const int tc12 = up ? t-12 : (t<12 ? t : 0);
      const int wb = up ? 2 : 0;
      const int koff = up ? 16 : 0;
      float cv[4]={0.f,0.f,0.f,0.f};
      for (int qb=0;qb<2;++qb){
        const uint4 wv = *(const uint4*)&WcL[(wb+qb)*48 + tc12*4];
        #pragma unroll
        for (int jc=0;jc<4;jc++){
          const uint4 av2 = *(const uint4*)&aH[wrow + r*4 + jc][koff + 8*qb];
          cv[jc]=FDOT2(asH2(wv.w), asH2(av2.w), FDOT2(asH2(wv.z), asH2(av2.z),
                  FDOT2(asH2(wv.y), asH2(av2.y), FDOT2(asH2(wv.x), asH2(av2.x), cv[jc]))));
        }
      }
      #pragma unroll
      for (int jc=0;jc<4;jc++){
        const int src = (t<12) ? t+12 : (up ? t-12 : t);
        float other = __shfl(cv[jc], src, 32);
        if (t<12) cS[(wrow + r*4 + jc)*12+t] = cv[jc]+other;
      }
    }
    // ---- offset accumulation (t<9) ----
    if (t<9){
      const int o=t/3, x=t-o*3;
      #pragma unroll
      for (int jc=0;jc<4;jc++){
        if (!vals[jc]) continue;
        const int row = wrow + r*4 + jc;
        const float dj = geoS[row][3];
        const float dh = geoS[row][x]/(dj+1e-8f);
        const float* cr = &cS[row*12];
        float val = cr[o]*dh;
        const float caxj = xjS[row][3+x];
        #pragma unroll
        for (int c=0;c<3;c++){
          val += cr[3+o*3+c]*(xjS[row][c*3+x]-caxj);
        }
        ofA += val;
      }
    }
  }

  stA += __shfl_xor(stA, 32);
  ofA += __shfl_xor(ofA, 32);
  if (wl < 16) part[s*28 + wl] = stA;
  if (wl < 9)  part[s*28 + 16 + wl] = ofA;
}

// ---------------- Kernel F: combine partials, scale by deg, form xyz_new ----------------
// grid = B*L (512), block = 64
__global__ __launch_bounds__(64) void k_fin(
    const float* __restrict__ xyz, const int* __restrict__ cnt,
    const float* __restrict__ part, float* __restrict__ out)
{
  const int bid = blockIdx.x;
  const int t = threadIdx.x;
  __shared__ float offF[9];
  const int n = cnt[bid];
  const float invd = 1.f/fmaxf((float)n,1.f);
  if (t<16){
    float s=0.f;
    #pragma unroll
    for (int k2=0;k2<SLI;k2++) s += part[(bid*SLI+k2)*28 + t];
    out[4608 + bid*16 + t] = s*invd;           // state
  } else if (t<25){
    float s=0.f;
    #pragma unroll
    for (int k2=0;k2<SLI;k2++) s += part[(bid*SLI+k2)*28 + t];
    offF[t-16] = s*invd;
  }
  __syncthreads();
  if (t<9){
    const int o=t/3, x=t-o*3;
    const float cac = xyz[(bid*3+1)*3+x];
    const float CA = cac + offF[3+x];          // offset[:,:,1]
    const float v = (o==1)? CA : (CA + offF[o*3+x]);
    out[bid*9 + t] = v;                        // xyz_new
  }
}

extern "C" void kernel_launch(void* const* d_in, const int* in_sizes, int n_in,
                              void* d_out, int out_size, void* d_ws, size_t ws_size,
                              hipStream_t stream)
{
  const float* msa     = (const float*)d_in[0];
  const float* pair    = (const float*)d_in[1];
  const float* xyz     = (const float*)d_in[2];
  const float* seq1hot = (const float*)d_in[3];
  const float* g_msa   = (const float*)d_in[4];
  const float* b_msa   = (const float*)d_in[5];
  const float* g_pair  = (const float*)d_in[6];
  const float* b_pair  = (const float*)d_in[7];
  const float* Wq      = (const float*)d_in[8];
  const float* bq      = (const float*)d_in[9];
  const float* Wk      = (const float*)d_in[10];
  const float* bk      = (const float*)d_in[11];
  const float* Wx      = (const float*)d_in[12];
  const float* bx      = (const float*)d_in[13];
  const float* g_node  = (const float*)d_in[14];
  const float* b_node  = (const float*)d_in[15];
  const float* We      = (const float*)d_in[16];
  const float* be      = (const float*)d_in[17];
  const float* g_edge  = (const float*)d_in[18];
  const float* b_edge  = (const float*)d_in[19];
  const float* Wa      = (const float*)d_in[20];
  const float* ba      = (const float*)d_in[21];
  const float* W0      = (const float*)d_in[22];
  const float* b0      = (const float*)d_in[23];
  const float* Wc1     = (const float*)d_in[24];
  const float* Wc2     = (const float*)d_in[25];
  const int*   idx     = (const int*)d_in[26];
  const int*   topk    = (const int*)d_in[27];
  float* out = (float*)d_out;

  float* wsf = (float*)d_ws;
  float*    node  = wsf + WS_NODE;
  int*      cnt   = (int*)(wsf + WS_CNT);
  int*      jlist = (int*)(wsf + WS_JLIST);
  float*    m0bG  = wsf + WS_M0B;
  float*    partb = wsf + WS_PART;
  unsigned* packW = (unsigned*)(wsf + WS_PACKW);

  k_prep<<<512, 512, 0, stream>>>(msa, seq1hot, xyz, idx, topk, g_msa, b_msa,
                                  Wq, bq, Wk, bk, Wx, bx, g_node, b_node,
                                  We, Wa, W0, b0, Wc1, Wc2,
                                  node, cnt, jlist, m0bG, packW);
  k_main<<<512*SLI/4, 256, 0, stream>>>(pair, xyz, g_pair, b_pair, be, g_edge,
                                        b_edge, ba, node, cnt, jlist, m0bG,
                                        packW, partb);
  k_fin<<<512, 64, 0, stream>>>(xyz, cnt, partb, out);
}

// Round 22
// 37.025 us; speedup vs baseline: 1.1215x; 1.0053x over previous
//
#include <hip/hip_runtime.h>

#define EPSLN 1e-5f
#define KMINC 9
#define SLI   10         // slices per (b,i), 8 rows each -> covers n <= 80

typedef _Float16 h2 __attribute__((ext_vector_type(2)));
typedef _Float16 h4 __attribute__((ext_vector_type(4)));

#if defined(__has_builtin)
#if __has_builtin(__builtin_amdgcn_fdot2)
#define FDOT2(a,b,c) __builtin_amdgcn_fdot2((a),(b),(c),false)
#endif
#endif
#ifndef FDOT2
#define FDOT2(a,b,c) ((c) + (float)(a)[0]*(float)(b)[0] + (float)(a)[1]*(float)(b)[1])
#endif

__device__ __forceinline__ h2 mk2(float a, float b){
  h2 v; v[0]=(_Float16)a; v[1]=(_Float16)b; return v;
}
__device__ __forceinline__ unsigned h2bits(h2 v){
  union { h2 h; unsigned u; } c; c.h = v; return c.u;
}
__device__ __forceinline__ h2 asH2(unsigned u){
  union { unsigned u; h2 h; } c; c.u = u; return c.h;
}

// ---- DPP-based reductions (r17-verified): butterflies on the VALU pipe ----
template<int CTRL>
__device__ __forceinline__ float dppadd(float v){
  union { float f; int i; } a, r;
  a.f = v;
  r.i = __builtin_amdgcn_update_dpp(a.i, a.i, CTRL, 0xf, 0xf, true);
  return v + r.f;
}
__device__ __forceinline__ float wred16d(float v){
  v = dppadd<0x0B1>(v);
  v = dppadd<0x04E>(v);
  v = dppadd<0x124>(v);
  v = dppadd<0x128>(v);
  return v;
}
__device__ __forceinline__ float wred32(float v){
  v = wred16d(v);
  return v + __shfl_xor(v, 16, 64);
}
__device__ __forceinline__ float wred64(float v){
  v = wred16d(v);
  v += __shfl_xor(v, 16, 64);
  return v + __shfl_xor(v, 32, 64);
}

// ws word-offsets
#define WS_NODE   0
#define WS_CNT    16384
#define WS_JLIST  16896       // 512*96 ints
#define WS_M0B    66048       // 512*16 f32
#define WS_PART   74240       // 512*SLI*28 f32 = 143360
#define WS_PACKW  217600      // q-blocked packed weights (3552 u32)

// ---------------- Kernel P: msa-LN/attention/node + m0b + top-k mask + weight packing ----------------
// grid = B*L (512), block = 512 (8 waves). r20: phase-2 loads hoisted to top.
// r21: msa rows + Wq/Wk weights preloaded into registers at kernel top, so the
// barrier-to-barrier phases contain no global-latency heads.
__global__ __launch_bounds__(512) void k_prep(
    const float* __restrict__ msa, const float* __restrict__ seq1hot,
    const float* __restrict__ xyz, const int* __restrict__ idxp,
    const int* __restrict__ topk,
    const float* __restrict__ g_msa, const float* __restrict__ b_msa,
    const float* __restrict__ Wq, const float* __restrict__ bq,
    const float* __restrict__ Wk, const float* __restrict__ bk,
    const float* __restrict__ Wx, const float* __restrict__ bx,
    const float* __restrict__ g_node, const float* __restrict__ b_node,
    const float* __restrict__ We, const float* __restrict__ Wa,
    const float* __restrict__ W0, const float* __restrict__ b0,
    const float* __restrict__ Wc1, const float* __restrict__ Wc2,
    float* __restrict__ node, int* __restrict__ cnt, int* __restrict__ jlist,
    float* __restrict__ m0bG, unsigned* __restrict__ packW)
{
  const int bid = blockIdx.x;          // b*256 + l  (l == i)
  const int b = bid >> 8;
  const int tid = threadIdx.x;
  const int w = tid >> 6, lane = tid & 63;   // 8 waves

  __shared__ float mn[32][64];
  __shared__ float qS[64];
  __shared__ float scS[32];
  __shared__ float redS[8][64];
  __shared__ float ssumS[8];
  __shared__ float nodeS[32];
  __shared__ alignas(16) float Dv[256];
  __shared__ int   rankS[256];
  __shared__ int   wsum[4];

  // ---- r20/r21: hoist ALL independent global loads to the very top ----
  const bool act = tid < 256;
  const int i = bid & 255;
  const int j8 = tid & 255;
  int sepE = 0, KE = 64;
  if (act){
    const float cax = xyz[(bid*3+1)*3+0];
    const float cay = xyz[(bid*3+1)*3+1];
    const float caz = xyz[(bid*3+1)*3+2];
    const int jb = (b<<8)+j8;
    float dx = xyz[(jb*3+1)*3+0]-cax;
    float dy = xyz[(jb*3+1)*3+1]-cay;
    float dz = xyz[(jb*3+1)*3+2]-caz;
    Dv[j8] = sqrtf(dx*dx+dy*dy+dz*dz) + (i==j8 ? 999.9f : 0.f);
    sepE = abs(idxp[jb] - idxp[bid]);
    int K = topk[0];
    if (K<=0 || K>256){
      float f = ((const float*)topk)[0];
      K = (f>=1.f && f<=256.f) ? (int)f : 64;
    }
    KE = K;
  }
  // r21: msa rows for this wave (loads issue here; reductions later)
  float msav[4];
  #pragma unroll
  for (int k=0;k<4;k++)
    msav[k] = msa[(size_t)(((b*32+(w+8*k))<<8)+(bid&255))*64 + lane];
  // r21: Wq/Wk slices for this wave's q/qk partials
  float wqv[8], wkv[8];
  #pragma unroll
  for (int d=0;d<8;d++){
    wqv[d] = Wq[(w*8+d)*64 + lane];
    wkv[d] = Wk[lane*64 + (w*8+d)];
  }

  // ---- block 0 packs weights q-blocked f16 into ws (for k_main) ----
  if (bid==0){
    for (int i2=tid;i2<2048;i2+=512){
      int qb=i2>>7, r7=i2&127, t=r7>>2, ii=r7&3, q=4*qb+ii;
      packW[i2] = h2bits(mk2(We[(2*q)*32+t], We[(2*q+1)*32+t]));
    }
    for (int i2=tid;i2<512; i2+=512){
      int qb=i2>>7, r7=i2&127, t=r7>>2, ii=r7&3, q=4*qb+ii;
      packW[2048+i2] = h2bits(mk2(Wa[(2*q)*32+t], Wa[(2*q+1)*32+t]));
    }
    for (int i2=tid;i2<768; i2+=512){
      int qb=i2>>6, r6=i2&63, tc=r6>>2, ii=r6&3, q=4*qb+ii;
      packW[2560+i2] = h2bits(mk2(W0[(2*q)*16+tc], W0[(2*q+1)*16+tc]));
    }
    if (tid<192){
      int qb=tid/48, r48=tid%48, tc=r48>>2, ii=r48&3, q=4*qb+ii;
      float lo = (tc<3)? Wc1[(2*q)*3+tc]   : Wc2[(2*q)*9+(tc-3)];
      float hi = (tc<3)? Wc1[(2*q+1)*3+tc] : Wc2[(2*q+1)*9+(tc-3)];
      packW[3328+tid] = h2bits(mk2(lo,hi));
    }
    if (tid<32) ((float*)packW)[3520+tid] = Wa[32*32+tid];
  }

  // ---- msa LN: wave w rows w, w+8, w+16, w+24 (from preloaded registers) ----
  const float gm = g_msa[lane], bm = b_msa[lane];
  #pragma unroll
  for (int k=0;k<4;k++){
    const int nn = w + 8*k;
    float x = msav[k];
    float s = wred64(x), s2 = wred64(x*x);
    float mu = s*(1.f/64.f);
    float var = s2*(1.f/64.f) - mu*mu;
    mn[nn][lane] = (x-mu)*rsqrtf(var+EPSLN)*gm + bm;
  }
  __syncthreads();
  // ---- q[e=lane]: partial over d-range per wave (weights preloaded) ----
  {
    float p = (w==0)? bq[lane] : 0.f;
    #pragma unroll
    for (int d=0;d<8;d++) p += mn[0][w*8+d]*wqv[d];
    redS[w][lane] = p;
  }
  __syncthreads();
  if (w==0){
    float q = 0.f;
    #pragma unroll
    for (int k=0;k<8;k++) q += redS[k][lane];
    qS[lane] = q*0.125f;               // 1/sqrt(64)
  }
  __syncthreads();
  // ---- qk[d=lane]: partial over e-range per wave (weights preloaded) ----
  {
    float p = 0.f;
    #pragma unroll
    for (int e=0;e<8;e++) p += wkv[e]*qS[w*8+e];
    redS[w][lane] = p;
  }
  __syncthreads();
  float qk = 0.f;
  #pragma unroll
  for (int k=0;k<8;k++) qk += redS[k][lane];
  const float qb_ = wred64(qS[lane]*bk[lane]);
  // ---- scores: wave w rows w*4..w*4+3 ----
  for (int nn=w*4; nn<w*4+4; nn++){
    float p = wred64(mn[nn][lane]*qk);
    if (lane==0) scS[nn] = p + qb_;
  }
  __syncthreads();
  // ---- softmax + weighted msa ----
  float mx = -1e30f;
  for (int nn=0; nn<32; nn++) mx = fmaxf(mx, scS[nn]);
  float ps=0.f, pm=0.f;
  for (int nn=w*4; nn<w*4+4; nn++){
    float e = expf(scS[nn]-mx);
    ps += e; pm += e*mn[nn][lane];
  }
  redS[w][lane] = pm;
  if (lane==0) ssumS[w] = ps;
  __syncthreads();
  if (w==0){
    float ssum = 0.f, acc = 0.f;
    #pragma unroll
    for (int k=0;k<8;k++){ ssum += ssumS[k]; acc += redS[k][lane]; }
    qS[lane] = acc / ssum;
  }
  __syncthreads();
  if (tid<32){
    float acc = bx[tid];
    for (int k=0;k<64;k++) acc += qS[k]*Wx[k*32+tid];
    const float* s1 = &seq1hot[bid*21];
    for (int k=0;k<21;k++) acc += s1[k]*Wx[(64+k)*32+tid];
    float s = wred32(acc), s2 = wred32(acc*acc);
    float mu = s*(1.f/32.f), var = s2*(1.f/32.f)-mu*mu;
    float v = (acc-mu)*rsqrtf(var+EPSLN)*g_node[tid] + b_node[tid];
    node[bid*32+tid] = v;
    nodeS[tid] = v;
  }
  __syncthreads();
  if (tid<16){
    float acc = b0[tid];
    for (int k=0;k<32;k++) acc += nodeS[k]*W0[(32+k)*16+tid];
    m0bG[bid*16+tid] = acc;
  }
  __syncthreads();        // publish Dv (written at top) to all threads

  // --- Phase 2: split rank scan (both halves, race-free) + compaction ---
  int rankLo = 0;
  {
    const float Dj = Dv[j8];
    const int base = (tid >> 8) * 128;     // 0 for lower half, 128 for upper half
    int rank = 0;
    for (int j2=base; j2<base+128; j2+=4){
      const float4 dv = *(const float4*)&Dv[j2];
      rank += (dv.x < Dj || (dv.x == Dj && (j2+0) < j8)) ? 1 : 0;
      rank += (dv.y < Dj || (dv.y == Dj && (j2+1) < j8)) ? 1 : 0;
      rank += (dv.z < Dj || (dv.z == Dj && (j2+2) < j8)) ? 1 : 0;
      rank += (dv.w < Dj || (dv.w == Dj && (j2+3) < j8)) ? 1 : 0;
    }
    if (!act) rankS[j8] = rank;            // upper half deposits its partial
    else      rankLo = rank;               // lower half keeps it in register
  }
  __syncthreads();
  if (act){
    const int rank = rankLo + rankS[j8];
    const bool m = (rank < KE) || (i!=j8 && sepE < KMINC);
    unsigned long long bal = __ballot(m);
    const int l6 = j8 & 63, wv = j8 >> 6;
    const int pre = __popcll(bal & ((1ull<<l6)-1ull));
    if (l6==0) wsum[wv] = __popcll(bal);
    __syncthreads();
    int off = 0;
    for (int w2=0;w2<wv;w2++) off += wsum[w2];
    if (m) jlist[bid*96 + off + pre] = j8;
    if (j8==0) cnt[bid] = wsum[0]+wsum[1]+wsum[2]+wsum[3];
  } else {
    __syncthreads();
  }
}

// ---------------- Kernel C: wave-per-slice gathered pipeline, b128 LDS (r20-verified) ----------------
// grid = 512*SLI/4 (1280), block = 256 = 4 independent waves; wave = one 8-row slice.
// r20: cnt/jlist/pair/node gathers hoisted before weight copy. r21: xyz gathers
// (xjS rows + t==0 geometry trio + CA_i) hoisted into the same pre-barrier phase.
__global__ __launch_bounds__(256) void k_main(
    const float* __restrict__ pair, const float* __restrict__ xyz,
    const float* __restrict__ g_pair, const float* __restrict__ b_pair,
    const float* __restrict__ be, const float* __restrict__ g_edge,
    const float* __restrict__ b_edge, const float* __restrict__ ba,
    const float* __restrict__ node, const int* __restrict__ cnt,
    const int* __restrict__ jlist, const float* __restrict__ m0bG,
    const unsigned* __restrict__ packW, float* __restrict__ part)
{
  const int tid = threadIdx.x;
  const int w  = tid >> 6;          // wave 0..3
  const int wl = tid & 63;          // lane in wave
  const int r  = (tid >> 5) & 1;    // group in wave
  const int t  = tid & 31;          // lane in group

  __shared__ alignas(16) unsigned WeL[2048];        // 8 KB q-blocked
  __shared__ alignas(16) unsigned WaL[512];         // 2 KB
  __shared__ alignas(16) unsigned W0L[768];         // 3 KB
  __shared__ alignas(16) unsigned WcL[192];         // 768 B
  __shared__ float waD[32];
  __shared__ float beS[32], geS[32], beeS[32], baS[32];
  __shared__ alignas(16) _Float16 pnH[32][128];     // 8 KB
  __shared__ alignas(16) _Float16 edH[32][32];      // 2 KB
  __shared__ alignas(16) _Float16 aH [32][32];      // 2 KB
  __shared__ alignas(16) _Float16 ndH[32][32];      // 2 KB
  __shared__ float cS[32*12];
  __shared__ float xjS[32][9];
  __shared__ float geoS[32][4];

  const int s    = blockIdx.x*4 + w;   // slice id
  const int item = s / SLI;            // (b,i)
  const int sl   = s - item*SLI;
  const int b    = item >> 8;
  const int row0 = sl*8;
  const int wrow = w*8;

  // ---- r20/r21: hoisted dependent-load chain (before weight copy) ----
  const int n = cnt[item];
  const float cax = xyz[(item*3+1)*3+0];
  const float cay = xyz[(item*3+1)*3+1];
  const float caz = xyz[(item*3+1)*3+2];
  bool vals[4]; int jjs[4];
  float4 pvv[4]; float nvv[4]; float xjv[4];
  float gxa[4], gya[4], gza[4];
  #pragma unroll
  for (int jc=0;jc<4;jc++){
    const int slot = row0 + r*4 + jc;
    vals[jc] = slot < n;
    jjs[jc] = jlist[item*96 + slot] & 255;     // memory-safe clamp; garbage gated later
  }
  #pragma unroll
  for (int jc=0;jc<4;jc++){
    const int jb = (b<<8)+jjs[jc];
    pvv[jc] = *(const float4*)&pair[(((long)item*256 + jjs[jc])*128) + 4*t];
    nvv[jc] = node[jb*32 + t];
    xjv[jc] = (t<9) ? xyz[(size_t)jb*9 + t] : 0.f;
    gxa[jc]=0.f; gya[jc]=0.f; gza[jc]=0.f;
    if (t==0){
      gxa[jc] = xyz[(size_t)jb*9+3];
      gya[jc] = xyz[(size_t)jb*9+4];
      gza[jc] = xyz[(size_t)jb*9+5];
    }
  }

  // ---- vectorized weight copy (uint4) — executes under the gather latency ----
  {
    const uint4* p4 = (const uint4*)packW;
    #pragma unroll
    for (int i2=tid;i2<512;i2+=256) ((uint4*)WeL)[i2] = p4[i2];
    if (tid<128) ((uint4*)WaL)[tid] = p4[512+tid];
    if (tid<192) ((uint4*)W0L)[tid] = p4[640+tid];
    if (tid<48)  ((uint4*)WcL)[tid] = p4[832+tid];
  }
  if (tid<32){
    waD[tid] = ((const float*)packW)[3520+tid];
    beS[tid]=be[tid]; geS[tid]=g_edge[tid]; beeS[tid]=b_edge[tid]; baS[tid]=ba[tid];
  }
  __syncthreads();        // the ONLY block-wide barrier

  float stA = 0.f;
  float ofA = 0.f;

  if (row0 < n){
    // ---- stage 4 rows per group (from preloaded registers) ----
    {
      const float4 gp4 = *(const float4*)&g_pair[4*t];
      const float4 bp4 = *(const float4*)&b_pair[4*t];
      #pragma unroll
      for (int jc=0;jc<4;jc++){
        const int row = wrow + r*4 + jc;
        const float4 pv4 = pvv[jc];
        float sm  = wred32(pv4.x+pv4.y+pv4.z+pv4.w);
        float sm2 = wred32(pv4.x*pv4.x+pv4.y*pv4.y+pv4.z*pv4.z+pv4.w*pv4.w);
        float mu = sm*(1.f/128.f);
        float var = sm2*(1.f/128.f)-mu*mu;
        float rs = rsqrtf(var+EPSLN);
        h4 o;
        o[0]=(_Float16)((pv4.x-mu)*rs*gp4.x+bp4.x);
        o[1]=(_Float16)((pv4.y-mu)*rs*gp4.y+bp4.y);
        o[2]=(_Float16)((pv4.z-mu)*rs*gp4.z+bp4.z);
        o[3]=(_Float16)((pv4.w-mu)*rs*gp4.w+bp4.w);
        *(h4*)&pnH[row][4*t] = o;
        ndH[row][t] = (_Float16)nvv[jc];
        if (t<9) xjS[row][t] = xjv[jc];
        if (t==0){
          float jx = gxa[jc]-cax;
          float jy = gya[jc]-cay;
          float jz = gza[jc]-caz;
          geoS[row][0]=jx; geoS[row][1]=jy; geoS[row][2]=jz;
          geoS[row][3]=sqrtf(jx*jx+jy*jy+jz*jz);
        }
      }
    }
    // ---- edge GEMV (128->32): 16 iters, all-b128 ----
    float ea0[4], ea1[4];
    #pragma unroll
    for (int jc=0;jc<4;jc++){ ea0[jc]=beS[t]; ea1[jc]=0.f; }
    for (int qb=0; qb<16; ++qb){
      const uint4 wv = *(const uint4*)&WeL[qb*128 + t*4];
      #pragma unroll
      for (int jc=0;jc<4;jc++){
        const uint4 pv = *(const uint4*)&pnH[wrow + r*4 + jc][8*qb];
        ea0[jc]=FDOT2(asH2(wv.y), asH2(pv.y), FDOT2(asH2(wv.x), asH2(pv.x), ea0[jc]));
        ea1[jc]=FDOT2(asH2(wv.w), asH2(pv.w), FDOT2(asH2(wv.z), asH2(pv.z), ea1[jc]));
      }
    }
    // ---- edge LN -> edH f16 ----
    #pragma unroll
    for (int jc=0;jc<4;jc++){
      float acc=ea0[jc]+ea1[jc];
      float sm=wred32(acc), sm2=wred32(acc*acc);
      float mu=sm*(1.f/32.f), var=sm2*(1.f/32.f)-mu*mu;
      edH[wrow + r*4 + jc][t] = (_Float16)((acc-mu)*rsqrtf(var+EPSLN)*geS[t]+beeS[t]);
    }
    // ---- a = relu([edge, dist] @ Wa + ba) ----
    float av[4];
    #pragma unroll
    for (int jc=0;jc<4;jc++) av[jc]=baS[t]+geoS[wrow + r*4 + jc][3]*waD[t];
    for (int qb=0; qb<4; ++qb){
      const uint4 wv = *(const uint4*)&WaL[qb*128 + t*4];
      #pragma unroll
      for (int jc=0;jc<4;jc++){
        const uint4 ev = *(const uint4*)&edH[wrow + r*4 + jc][8*qb];
        av[jc]=FDOT2(asH2(wv.w), asH2(ev.w), FDOT2(asH2(wv.z), asH2(ev.z),
                FDOT2(asH2(wv.y), asH2(ev.y), FDOT2(asH2(wv.x), asH2(ev.x), av[jc]))));
      }
    }
    #pragma unroll
    for (int jc=0;jc<4;jc++) aH[wrow + r*4 + jc][t]=(_Float16)fmaxf(av[jc],0.f);
    // ---- m0: a-part lanes t<16 (W0 blocks 0..3), node-part t>=16 (blocks 8..11) ----
    {
      const int half = t>>4, tc = t&15;
      const int wb = half ? 8 : 0;
      const float m0b = half ? 0.f : m0bG[item*16+tc];
      float m0v[4];
      #pragma unroll
      for (int jc=0;jc<4;jc++) m0v[jc]=m0b;
      for (int qb=0;qb<4;++qb){
        const uint4 wv = *(const uint4*)&W0L[(wb+qb)*64 + tc*4];
        #pragma unroll
        for (int jc=0;jc<4;jc++){
          const _Float16* opb = half ? &ndH[wrow + r*4 + jc][0] : &aH[wrow + r*4 + jc][0];
          const uint4 ov = *(const uint4*)&opb[8*qb];
          m0v[jc]=FDOT2(asH2(wv.w), asH2(ov.w), FDOT2(asH2(wv.z), asH2(ov.z),
                   FDOT2(asH2(wv.y), asH2(ov.y), FDOT2(asH2(wv.x), asH2(ov.x), m0v[jc]))));
        }
      }
      #pragma unroll
      for (int jc=0;jc<4;jc++){
        float tot = m0v[jc] + __shfl_xor(m0v[jc], 16);
        if (t<16 && vals[jc]) stA += fmaxf(tot, 0.f);
      }
    }
    // ---- c1/c2 from a: lanes t<12 k-rows 0..15 (blocks 0..1), lanes 12..23 k 16..31 (blocks 2..3) ----
    {
      const bool up = (t>=12 && t<24);
      const int tc12 = up ? t-12 : (t<12 ? t : 0);
      const int wb = up ? 2 : 0;
      const int koff = up ? 16 : 0;
      float cv[4]={0.f,0.f,0.f,0.f};
      for (int qb=0;qb<2;++qb){
        const uint4 wv = *(const uint4*)&WcL[(wb+qb)*48 + tc12*4];
        #pragma unroll
        for (int jc=0;jc<4;jc++){
          const uint4 av2 = *(const uint4*)&aH[wrow + r*4 + jc][koff + 8*qb];
          cv[jc]=FDOT2(asH2(wv.w), asH2(av2.w), FDOT2(asH2(wv.z), asH2(av2.z),
                  FDOT2(asH2(wv.y), asH2(av2.y), FDOT2(asH2(wv.x), asH2(av2.x), cv[jc]))));
        }
      }
      #pragma unroll
      for (int jc=0;jc<4;jc++){
        const int src = (t<12) ? t+12 : (up ? t-12 : t);
        float other = __shfl(cv[jc], src, 32);
        if (t<12) cS[(wrow + r*4 + jc)*12+t] = cv[jc]+other;
      }
    }
    // ---- offset accumulation (t<9) ----
    if (t<9){
      const int o=t/3, x=t-o*3;
      #pragma unroll
      for (int jc=0;jc<4;jc++){
        if (!vals[jc]) continue;
        const int row = wrow + r*4 + jc;
        const float dj = geoS[row][3];
        const float dh = geoS[row][x]/(dj+1e-8f);
        const float* cr = &cS[row*12];
        float val = cr[o]*dh;
        const float caxj = xjS[row][3+x];
        #pragma unroll
        for (int c=0;c<3;c++){
          val += cr[3+o*3+c]*(xjS[row][c*3+x]-caxj);
        }
        ofA += val;
      }
    }
  }

  stA += __shfl_xor(stA, 32);
  ofA += __shfl_xor(ofA, 32);
  if (wl < 16) part[s*28 + wl] = stA;
  if (wl < 9)  part[s*28 + 16 + wl] = ofA;
}

// ---------------- Kernel F: combine partials, scale by deg, form xyz_new ----------------
// grid = B*L (512), block = 64
__global__ __launch_bounds__(64) void k_fin(
    const float* __restrict__ xyz, const int* __restrict__ cnt,
    const float* __restrict__ part, float* __restrict__ out)
{
  const int bid = blockIdx.x;
  const int t = threadIdx.x;
  __shared__ float offF[9];
  const int n = cnt[bid];
  const float invd = 1.f/fmaxf((float)n,1.f);
  if (t<16){
    float s=0.f;
    #pragma unroll
    for (int k2=0;k2<SLI;k2++) s += part[(bid*SLI+k2)*28 + t];
    out[4608 + bid*16 + t] = s*invd;           // state
  } else if (t<25){
    float s=0.f;
    #pragma unroll
    for (int k2=0;k2<SLI;k2++) s += part[(bid*SLI+k2)*28 + t];
    offF[t-16] = s*invd;
  }
  __syncthreads();
  if (t<9){
    const int o=t/3, x=t-o*3;
    const float cac = xyz[(bid*3+1)*3+x];
    const float CA = cac + offF[3+x];          // offset[:,:,1]
    const float v = (o==1)? CA : (CA + offF[o*3+x]);
    out[bid*9 + t] = v;                        // xyz_new
  }
}

extern "C" void kernel_launch(void* const* d_in, const int* in_sizes, int n_in,
                              void* d_out, int out_size, void* d_ws, size_t ws_size,
                              hipStream_t stream)
{
  const float* msa     = (const float*)d_in[0];
  const float* pair    = (const float*)d_in[1];
  const float* xyz     = (const float*)d_in[2];
  const float* seq1hot = (const float*)d_in[3];
  const float* g_msa   = (const float*)d_in[4];
  const float* b_msa   = (const float*)d_in[5];
  const float* g_pair  = (const float*)d_in[6];
  const float* b_pair  = (const float*)d_in[7];
  const float* Wq      = (const float*)d_in[8];
  const float* bq      = (const float*)d_in[9];
  const float* Wk      = (const float*)d_in[10];
  const float* bk      = (const float*)d_in[11];
  const float* Wx      = (const float*)d_in[12];
  const float* bx      = (const float*)d_in[13];
  const float* g_node  = (const float*)d_in[14];
  const float* b_node  = (const float*)d_in[15];
  const float* We      = (const float*)d_in[16];
  const float* be      = (const float*)d_in[17];
  const float* g_edge  = (const float*)d_in[18];
  const float* b_edge  = (const float*)d_in[19];
  const float* Wa      = (const float*)d_in[20];
  const float* ba      = (const float*)d_in[21];
  const float* W0      = (const float*)d_in[22];
  const float* b0      = (const float*)d_in[23];
  const float* Wc1     = (const float*)d_in[24];
  const float* Wc2     = (const float*)d_in[25];
  const int*   idx     = (const int*)d_in[26];
  const int*   topk    = (const int*)d_in[27];
  float* out = (float*)d_out;

  float* wsf = (float*)d_ws;
  float*    node  = wsf + WS_NODE;
  int*      cnt   = (int*)(wsf + WS_CNT);
  int*      jlist = (int*)(wsf + WS_JLIST);
  float*    m0bG  = wsf + WS_M0B;
  float*    partb = wsf + WS_PART;
  unsigned* packW = (unsigned*)(wsf + WS_PACKW);

  k_prep<<<512, 512, 0, stream>>>(msa, seq1hot, xyz, idx, topk, g_msa, b_msa,
                                  Wq, bq, Wk, bk, Wx, bx, g_node, b_node,
                                  We, Wa, W0, b0, Wc1, Wc2,
                                  node, cnt, jlist, m0bG, packW);
  k_main<<<512*SLI/4, 256, 0, stream>>>(pair, xyz, g_pair, b_pair, be, g_edge,
                                        b_edge, ba, node, cnt, jlist, m0bG,
                                        packW, partb);
  k_fin<<<512, 64, 0, stream>>>(xyz, cnt, partb, out);
}

// Round 23
// 37.012 us; speedup vs baseline: 1.1219x; 1.0003x over previous
//
#include <hip/hip_runtime.h>

#define EPSLN 1e-5f
#define KMINC 9
#define SLI   10         // slices per (b,i), 8 rows each -> covers n <= 80

typedef _Float16 h2 __attribute__((ext_vector_type(2)));
typedef _Float16 h4 __attribute__((ext_vector_type(4)));

#if defined(__has_builtin)
#if __has_builtin(__builtin_amdgcn_fdot2)
#define FDOT2(a,b,c) __builtin_amdgcn_fdot2((a),(b),(c),false)
#endif
#endif
#ifndef FDOT2
#define FDOT2(a,b,c) ((c) + (float)(a)[0]*(float)(b)[0] + (float)(a)[1]*(float)(b)[1])
#endif

__device__ __forceinline__ h2 mk2(float a, float b){
  h2 v; v[0]=(_Float16)a; v[1]=(_Float16)b; return v;
}
__device__ __forceinline__ unsigned h2bits(h2 v){
  union { h2 h; unsigned u; } c; c.h = v; return c.u;
}
__device__ __forceinline__ h2 asH2(unsigned u){
  union { unsigned u; h2 h; } c; c.u = u; return c.h;
}

// ---- DPP-based reductions (r17-verified): butterflies on the VALU pipe ----
template<int CTRL>
__device__ __forceinline__ float dppadd(float v){
  union { float f; int i; } a, r;
  a.f = v;
  r.i = __builtin_amdgcn_update_dpp(a.i, a.i, CTRL, 0xf, 0xf, true);
  return v + r.f;
}
__device__ __forceinline__ float wred16d(float v){
  v = dppadd<0x0B1>(v);
  v = dppadd<0x04E>(v);
  v = dppadd<0x124>(v);
  v = dppadd<0x128>(v);
  return v;
}
__device__ __forceinline__ float wred32(float v){
  v = wred16d(v);
  return v + __shfl_xor(v, 16, 64);
}
__device__ __forceinline__ float wred64(float v){
  v = wred16d(v);
  v += __shfl_xor(v, 16, 64);
  return v + __shfl_xor(v, 32, 64);
}

// ws word-offsets
#define WS_NODE   0
#define WS_CNT    16384
#define WS_JLIST  16896       // 512*96 ints
#define WS_M0B    66048       // 512*16 f32
#define WS_PART   74240       // 512*SLI*28 f32 = 143360
#define WS_PACKW  217600      // q-blocked packed weights (3552 u32)

// ---------------- Kernel P: msa-LN/attention/node + m0b + top-k mask + weight packing ----------------
// grid = B*L (512), block = 512 (8 waves). r20: phase-2 loads hoisted to top.
// r21: msa rows + Wq/Wk weights preloaded into registers at kernel top, so the
// barrier-to-barrier phases contain no global-latency heads.
__global__ __launch_bounds__(512) void k_prep(
    const float* __restrict__ msa, const float* __restrict__ seq1hot,
    const float* __restrict__ xyz, const int* __restrict__ idxp,
    const int* __restrict__ topk,
    const float* __restrict__ g_msa, const float* __restrict__ b_msa,
    const float* __restrict__ Wq, const float* __restrict__ bq,
    const float* __restrict__ Wk, const float* __restrict__ bk,
    const float* __restrict__ Wx, const float* __restrict__ bx,
    const float* __restrict__ g_node, const float* __restrict__ b_node,
    const float* __restrict__ We, const float* __restrict__ Wa,
    const float* __restrict__ W0, const float* __restrict__ b0,
    const float* __restrict__ Wc1, const float* __restrict__ Wc2,
    float* __restrict__ node, int* __restrict__ cnt, int* __restrict__ jlist,
    float* __restrict__ m0bG, unsigned* __restrict__ packW)
{
  const int bid = blockIdx.x;          // b*256 + l  (l == i)
  const int b = bid >> 8;
  const int tid = threadIdx.x;
  const int w = tid >> 6, lane = tid & 63;   // 8 waves

  __shared__ float mn[32][64];
  __shared__ float qS[64];
  __shared__ float scS[32];
  __shared__ float redS[8][64];
  __shared__ float ssumS[8];
  __shared__ float nodeS[32];
  __shared__ alignas(16) float Dv[256];
  __shared__ int   rankS[256];
  __shared__ int   wsum[4];

  // ---- r20/r21: hoist ALL independent global loads to the very top ----
  const bool act = tid < 256;
  const int i = bid & 255;
  const int j8 = tid & 255;
  int sepE = 0, KE = 64;
  if (act){
    const float cax = xyz[(bid*3+1)*3+0];
    const float cay = xyz[(bid*3+1)*3+1];
    const float caz = xyz[(bid*3+1)*3+2];
    const int jb = (b<<8)+j8;
    float dx = xyz[(jb*3+1)*3+0]-cax;
    float dy = xyz[(jb*3+1)*3+1]-cay;
    float dz = xyz[(jb*3+1)*3+2]-caz;
    Dv[j8] = sqrtf(dx*dx+dy*dy+dz*dz) + (i==j8 ? 999.9f : 0.f);
    sepE = abs(idxp[jb] - idxp[bid]);
    int K = topk[0];
    if (K<=0 || K>256){
      float f = ((const float*)topk)[0];
      K = (f>=1.f && f<=256.f) ? (int)f : 64;
    }
    KE = K;
  }
  // r21: msa rows for this wave (loads issue here; reductions later)
  float msav[4];
  #pragma unroll
  for (int k=0;k<4;k++)
    msav[k] = msa[(size_t)(((b*32+(w+8*k))<<8)+(bid&255))*64 + lane];
  // r21: Wq/Wk slices for this wave's q/qk partials
  float wqv[8], wkv[8];
  #pragma unroll
  for (int d=0;d<8;d++){
    wqv[d] = Wq[(w*8+d)*64 + lane];
    wkv[d] = Wk[lane*64 + (w*8+d)];
  }

  // ---- block 0 packs weights q-blocked f16 into ws (for k_main) ----
  if (bid==0){
    for (int i2=tid;i2<2048;i2+=512){
      int qb=i2>>7, r7=i2&127, t=r7>>2, ii=r7&3, q=4*qb+ii;
      packW[i2] = h2bits(mk2(We[(2*q)*32+t], We[(2*q+1)*32+t]));
    }
    for (int i2=tid;i2<512; i2+=512){
      int qb=i2>>7, r7=i2&127, t=r7>>2, ii=r7&3, q=4*qb+ii;
      packW[2048+i2] = h2bits(mk2(Wa[(2*q)*32+t], Wa[(2*q+1)*32+t]));
    }
    for (int i2=tid;i2<768; i2+=512){
      int qb=i2>>6, r6=i2&63, tc=r6>>2, ii=r6&3, q=4*qb+ii;
      packW[2560+i2] = h2bits(mk2(W0[(2*q)*16+tc], W0[(2*q+1)*16+tc]));
    }
    if (tid<192){
      int qb=tid/48, r48=tid%48, tc=r48>>2, ii=r48&3, q=4*qb+ii;
      float lo = (tc<3)? Wc1[(2*q)*3+tc]   : Wc2[(2*q)*9+(tc-3)];
      float hi = (tc<3)? Wc1[(2*q+1)*3+tc] : Wc2[(2*q+1)*9+(tc-3)];
      packW[3328+tid] = h2bits(mk2(lo,hi));
    }
    if (tid<32) ((float*)packW)[3520+tid] = Wa[32*32+tid];
  }

  // ---- msa LN: wave w rows w, w+8, w+16, w+24 (from preloaded registers) ----
  const float gm = g_msa[lane], bm = b_msa[lane];
  #pragma unroll
  for (int k=0;k<4;k++){
    const int nn = w + 8*k;
    float x = msav[k];
    float s = wred64(x), s2 = wred64(x*x);
    float mu = s*(1.f/64.f);
    float var = s2*(1.f/64.f) - mu*mu;
    mn[nn][lane] = (x-mu)*rsqrtf(var+EPSLN)*gm + bm;
  }
  __syncthreads();
  // ---- q[e=lane]: partial over d-range per wave (weights preloaded) ----
  {
    float p = (w==0)? bq[lane] : 0.f;
    #pragma unroll
    for (int d=0;d<8;d++) p += mn[0][w*8+d]*wqv[d];
    redS[w][lane] = p;
  }
  __syncthreads();
  if (w==0){
    float q = 0.f;
    #pragma unroll
    for (int k=0;k<8;k++) q += redS[k][lane];
    qS[lane] = q*0.125f;               // 1/sqrt(64)
  }
  __syncthreads();
  // ---- qk[d=lane]: partial over e-range per wave (weights preloaded) ----
  {
    float p = 0.f;
    #pragma unroll
    for (int e=0;e<8;e++) p += wkv[e]*qS[w*8+e];
    redS[w][lane] = p;
  }
  __syncthreads();
  float qk = 0.f;
  #pragma unroll
  for (int k=0;k<8;k++) qk += redS[k][lane];
  const float qb_ = wred64(qS[lane]*bk[lane]);
  // ---- scores: wave w rows w*4..w*4+3 ----
  for (int nn=w*4; nn<w*4+4; nn++){
    float p = wred64(mn[nn][lane]*qk);
    if (lane==0) scS[nn] = p + qb_;
  }
  __syncthreads();
  // ---- softmax + weighted msa ----
  float mx = -1e30f;
  for (int nn=0; nn<32; nn++) mx = fmaxf(mx, scS[nn]);
  float ps=0.f, pm=0.f;
  for (int nn=w*4; nn<w*4+4; nn++){
    float e = expf(scS[nn]-mx);
    ps += e; pm += e*mn[nn][lane];
  }
  redS[w][lane] = pm;
  if (lane==0) ssumS[w] = ps;
  __syncthreads();
  if (w==0){
    float ssum = 0.f, acc = 0.f;
    #pragma unroll
    for (int k=0;k<8;k++){ ssum += ssumS[k]; acc += redS[k][lane]; }
    qS[lane] = acc / ssum;
  }
  __syncthreads();
  if (tid<32){
    float acc = bx[tid];
    for (int k=0;k<64;k++) acc += qS[k]*Wx[k*32+tid];
    const float* s1 = &seq1hot[bid*21];
    for (int k=0;k<21;k++) acc += s1[k]*Wx[(64+k)*32+tid];
    float s = wred32(acc), s2 = wred32(acc*acc);
    float mu = s*(1.f/32.f), var = s2*(1.f/32.f)-mu*mu;
    float v = (acc-mu)*rsqrtf(var+EPSLN)*g_node[tid] + b_node[tid];
    node[bid*32+tid] = v;
    nodeS[tid] = v;
  }
  __syncthreads();
  if (tid<16){
    float acc = b0[tid];
    for (int k=0;k<32;k++) acc += nodeS[k]*W0[(32+k)*16+tid];
    m0bG[bid*16+tid] = acc;
  }
  __syncthreads();        // publish Dv (written at top) to all threads

  // --- Phase 2: split rank scan (both halves, race-free) + compaction ---
  int rankLo = 0;
  {
    const float Dj = Dv[j8];
    const int base = (tid >> 8) * 128;     // 0 for lower half, 128 for upper half
    int rank = 0;
    for (int j2=base; j2<base+128; j2+=4){
      const float4 dv = *(const float4*)&Dv[j2];
      rank += (dv.x < Dj || (dv.x == Dj && (j2+0) < j8)) ? 1 : 0;
      rank += (dv.y < Dj || (dv.y == Dj && (j2+1) < j8)) ? 1 : 0;
      rank += (dv.z < Dj || (dv.z == Dj && (j2+2) < j8)) ? 1 : 0;
      rank += (dv.w < Dj || (dv.w == Dj && (j2+3) < j8)) ? 1 : 0;
    }
    if (!act) rankS[j8] = rank;            // upper half deposits its partial
    else      rankLo = rank;               // lower half keeps it in register
  }
  __syncthreads();
  if (act){
    const int rank = rankLo + rankS[j8];
    const bool m = (rank < KE) || (i!=j8 && sepE < KMINC);
    unsigned long long bal = __ballot(m);
    const int l6 = j8 & 63, wv = j8 >> 6;
    const int pre = __popcll(bal & ((1ull<<l6)-1ull));
    if (l6==0) wsum[wv] = __popcll(bal);
    __syncthreads();
    int off = 0;
    for (int w2=0;w2<wv;w2++) off += wsum[w2];
    if (m) jlist[bid*96 + off + pre] = j8;
    if (j8==0) cnt[bid] = wsum[0]+wsum[1]+wsum[2]+wsum[3];
  } else {
    __syncthreads();
  }
}

// ---------------- Kernel C: wave-per-slice gathered pipeline, b128 LDS (r20-verified) ----------------
// grid = 512*SLI/4 (1280), block = 256 = 4 independent waves; wave = one 8-row slice.
// r20: cnt/jlist/pair/node gathers hoisted before weight copy. r21: xyz gathers
// (xjS rows + t==0 geometry trio + CA_i) hoisted into the same pre-barrier phase.
__global__ __launch_bounds__(256) void k_main(
    const float* __restrict__ pair, const float* __restrict__ xyz,
    const float* __restrict__ g_pair, const float* __restrict__ b_pair,
    const float* __restrict__ be, const float* __restrict__ g_edge,
    const float* __restrict__ b_edge, const float* __restrict__ ba,
    const float* __restrict__ node, const int* __restrict__ cnt,
    const int* __restrict__ jlist, const float* __restrict__ m0bG,
    const unsigned* __restrict__ packW, float* __restrict__ part)
{
  const int tid = threadIdx.x;
  const int w  = tid >> 6;          // wave 0..3
  const int wl = tid & 63;          // lane in wave
  const int r  = (tid >> 5) & 1;    // group in wave
  const int t  = tid & 31;          // lane in group

  __shared__ alignas(16) unsigned WeL[2048];        // 8 KB q-blocked
  __shared__ alignas(16) unsigned WaL[512];         // 2 KB
  __shared__ alignas(16) unsigned W0L[768];         // 3 KB
  __shared__ alignas(16) unsigned WcL[192];         // 768 B
  __shared__ float waD[32];
  __shared__ float beS[32], geS[32], beeS[32], baS[32];
  __shared__ alignas(16) _Float16 pnH[32][128];     // 8 KB
  __shared__ alignas(16) _Float16 edH[32][32];      // 2 KB
  __shared__ alignas(16) _Float16 aH [32][32];      // 2 KB
  __shared__ alignas(16) _Float16 ndH[32][32];      // 2 KB
  __shared__ float cS[32*12];
  __shared__ float xjS[32][9];
  __shared__ float geoS[32][4];

  const int s    = blockIdx.x*4 + w;   // slice id
  const int item = s / SLI;            // (b,i)
  const int sl   = s - item*SLI;
  const int b    = item >> 8;
  const int row0 = sl*8;
  const int wrow = w*8;

  // ---- r20/r21: hoisted dependent-load chain (before weight copy) ----
  const int n = cnt[item];
  const float cax = xyz[(item*3+1)*3+0];
  const float cay = xyz[(item*3+1)*3+1];
  const float caz = xyz[(item*3+1)*3+2];
  bool vals[4]; int jjs[4];
  float4 pvv[4]; float nvv[4]; float xjv[4];
  float gxa[4], gya[4], gza[4];
  #pragma unroll
  for (int jc=0;jc<4;jc++){
    const int slot = row0 + r*4 + jc;
    vals[jc] = slot < n;
    jjs[jc] = jlist[item*96 + slot] & 255;     // memory-safe clamp; garbage gated later
  }
  #pragma unroll
  for (int jc=0;jc<4;jc++){
    const int jb = (b<<8)+jjs[jc];
    pvv[jc] = *(const float4*)&pair[(((long)item*256 + jjs[jc])*128) + 4*t];
    nvv[jc] = node[jb*32 + t];
    xjv[jc] = (t<9) ? xyz[(size_t)jb*9 + t] : 0.f;
    gxa[jc]=0.f; gya[jc]=0.f; gza[jc]=0.f;
    if (t==0){
      gxa[jc] = xyz[(size_t)jb*9+3];
      gya[jc] = xyz[(size_t)jb*9+4];
      gza[jc] = xyz[(size_t)jb*9+5];
    }
  }

  // ---- vectorized weight copy (uint4) — executes under the gather latency ----
  {
    const uint4* p4 = (const uint4*)packW;
    #pragma unroll
    for (int i2=tid;i2<512;i2+=256) ((uint4*)WeL)[i2] = p4[i2];
    if (tid<128) ((uint4*)WaL)[tid] = p4[512+tid];
    if (tid<192) ((uint4*)W0L)[tid] = p4[640+tid];
    if (tid<48)  ((uint4*)WcL)[tid] = p4[832+tid];
  }
  if (tid<32){
    waD[tid] = ((const float*)packW)[3520+tid];
    beS[tid]=be[tid]; geS[tid]=g_edge[tid]; beeS[tid]=b_edge[tid]; baS[tid]=ba[tid];
  }
  __syncthreads();        // the ONLY block-wide barrier

  float stA = 0.f;
  float ofA = 0.f;

  if (row0 < n){
    // ---- stage 4 rows per group (from preloaded registers) ----
    {
      const float4 gp4 = *(const float4*)&g_pair[4*t];
      const float4 bp4 = *(const float4*)&b_pair[4*t];
      #pragma unroll
      for (int jc=0;jc<4;jc++){
        const int row = wrow + r*4 + jc;
        const float4 pv4 = pvv[jc];
        float sm  = wred32(pv4.x+pv4.y+pv4.z+pv4.w);
        float sm2 = wred32(pv4.x*pv4.x+pv4.y*pv4.y+pv4.z*pv4.z+pv4.w*pv4.w);
        float mu = sm*(1.f/128.f);
        float var = sm2*(1.f/128.f)-mu*mu;
        float rs = rsqrtf(var+EPSLN);
        h4 o;
        o[0]=(_Float16)((pv4.x-mu)*rs*gp4.x+bp4.x);
        o[1]=(_Float16)((pv4.y-mu)*rs*gp4.y+bp4.y);
        o[2]=(_Float16)((pv4.z-mu)*rs*gp4.z+bp4.z);
        o[3]=(_Float16)((pv4.w-mu)*rs*gp4.w+bp4.w);
        *(h4*)&pnH[row][4*t] = o;
        ndH[row][t] = (_Float16)nvv[jc];
        if (t<9) xjS[row][t] = xjv[jc];
        if (t==0){
          float jx = gxa[jc]-cax;
          float jy = gya[jc]-cay;
          float jz = gza[jc]-caz;
          geoS[row][0]=jx; geoS[row][1]=jy; geoS[row][2]=jz;
          geoS[row][3]=sqrtf(jx*jx+jy*jy+jz*jz);
        }
      }
    }
    // ---- edge GEMV (128->32): 16 iters, all-b128 ----
    float ea0[4], ea1[4];
    #pragma unroll
    for (int jc=0;jc<4;jc++){ ea0[jc]=beS[t]; ea1[jc]=0.f; }
    for (int qb=0; qb<16; ++qb){
      const uint4 wv = *(const uint4*)&WeL[qb*128 + t*4];
      #pragma unroll
      for (int jc=0;jc<4;jc++){
        const uint4 pv = *(const uint4*)&pnH[wrow + r*4 + jc][8*qb];
        ea0[jc]=FDOT2(asH2(wv.y), asH2(pv.y), FDOT2(asH2(wv.x), asH2(pv.x), ea0[jc]));
        ea1[jc]=FDOT2(asH2(wv.w), asH2(pv.w), FDOT2(asH2(wv.z), asH2(pv.z), ea1[jc]));
      }
    }
    // ---- edge LN -> edH f16 ----
    #pragma unroll
    for (int jc=0;jc<4;jc++){
      float acc=ea0[jc]+ea1[jc];
      float sm=wred32(acc), sm2=wred32(acc*acc);
      float mu=sm*(1.f/32.f), var=sm2*(1.f/32.f)-mu*mu;
      edH[wrow + r*4 + jc][t] = (_Float16)((acc-mu)*rsqrtf(var+EPSLN)*geS[t]+beeS[t]);
    }
    // ---- a = relu([edge, dist] @ Wa + ba) ----
    float av[4];
    #pragma unroll
    for (int jc=0;jc<4;jc++) av[jc]=baS[t]+geoS[wrow + r*4 + jc][3]*waD[t];
    for (int qb=0; qb<4; ++qb){
      const uint4 wv = *(const uint4*)&WaL[qb*128 + t*4];
      #pragma unroll
      for (int jc=0;jc<4;jc++){
        const uint4 ev = *(const uint4*)&edH[wrow + r*4 + jc][8*qb];
        av[jc]=FDOT2(asH2(wv.w), asH2(ev.w), FDOT2(asH2(wv.z), asH2(ev.z),
                FDOT2(asH2(wv.y), asH2(ev.y), FDOT2(asH2(wv.x), asH2(ev.x), av[jc]))));
      }
    }
    #pragma unroll
    for (int jc=0;jc<4;jc++) aH[wrow + r*4 + jc][t]=(_Float16)fmaxf(av[jc],0.f);
    // ---- m0: a-part lanes t<16 (W0 blocks 0..3), node-part t>=16 (blocks 8..11) ----
    {
      const int half = t>>4, tc = t&15;
      const int wb = half ? 8 : 0;
      const float m0b = half ? 0.f : m0bG[item*16+tc];
      float m0v[4];
      #pragma unroll
      for (int jc=0;jc<4;jc++) m0v[jc]=m0b;
      for (int qb=0;qb<4;++qb){
        const uint4 wv = *(const uint4*)&W0L[(wb+qb)*64 + tc*4];
        #pragma unroll
        for (int jc=0;jc<4;jc++){
          const _Float16* opb = half ? &ndH[wrow + r*4 + jc][0] : &aH[wrow + r*4 + jc][0];
          const uint4 ov = *(const uint4*)&opb[8*qb];
          m0v[jc]=FDOT2(asH2(wv.w), asH2(ov.w), FDOT2(asH2(wv.z), asH2(ov.z),
                   FDOT2(asH2(wv.y), asH2(ov.y), FDOT2(asH2(wv.x), asH2(ov.x), m0v[jc]))));
        }
      }
      #pragma unroll
      for (int jc=0;jc<4;jc++){
        float tot = m0v[jc] + __shfl_xor(m0v[jc], 16);
        if (t<16 && vals[jc]) stA += fmaxf(tot, 0.f);
      }
    }
    // ---- c1/c2 from a: lanes t<12 k-rows 0..15 (blocks 0..1), lanes 12..23 k 16..31 (blocks 2..3) ----
    {
      const bool up = (t>=12 && t<24);
      const int tc12 = up ? t-12 : (t<12 ? t : 0);
      const int wb = up ? 2 : 0;
      const int koff = up ? 16 : 0;
      float cv[4]={0.f,0.f,0.f,0.f};
      for (int qb=0;qb<2;++qb){
        const uint4 wv = *(const uint4*)&WcL[(wb+qb)*48 + tc12*4];
        #pragma unroll
        for (int jc=0;jc<4;jc++){
          const uint4 av2 = *(const uint4*)&aH[wrow + r*4 + jc][koff + 8*qb];
          cv[jc]=FDOT2(asH2(wv.w), asH2(av2.w), FDOT2(asH2(wv.z), asH2(av2.z),
                  FDOT2(asH2(wv.y), asH2(av2.y), FDOT2(asH2(wv.x), asH2(av2.x), cv[jc]))));
        }
      }
      #pragma unroll
      for (int jc=0;jc<4;jc++){
        const int src = (t<12) ? t+12 : (up ? t-12 : t);
        float other = __shfl(cv[jc], src, 32);
        if (t<12) cS[(wrow + r*4 + jc)*12+t] = cv[jc]+other;
      }
    }
    // ---- offset accumulation (t<9) ----
    if (t<9){
      const int o=t/3, x=t-o*3;
      #pragma unroll
      for (int jc=0;jc<4;jc++){
        if (!vals[jc]) continue;
        const int row = wrow + r*4 + jc;
        const float dj = geoS[row][3];
        const float dh = geoS[row][x]/(dj+1e-8f);
        const float* cr = &cS[row*12];
        float val = cr[o]*dh;
        const float caxj = xjS[row][3+x];
        #pragma unroll
        for (int c=0;c<3;c++){
          val += cr[3+o*3+c]*(xjS[row][c*3+x]-caxj);
        }
        ofA += val;
      }
    }
  }

  stA += __shfl_xor(stA, 32);
  ofA += __shfl_xor(ofA, 32);
  if (wl < 16) part[s*28 + wl] = stA;
  if (wl < 9)  part[s*28 + 16 + wl] = ofA;
}

// ---------------- Kernel F: combine partials, scale by deg, form xyz_new ----------------
// grid = B*L (512), block = 64
__global__ __launch_bounds__(64) void k_fin(
    const float* __restrict__ xyz, const int* __restrict__ cnt,
    const float* __restrict__ part, float* __restrict__ out)
{
  const int bid = blockIdx.x;
  const int t = threadIdx.x;
  __shared__ float offF[9];
  const int n = cnt[bid];
  const float invd = 1.f/fmaxf((float)n,1.f);
  if (t<16){
    float s=0.f;
    #pragma unroll
    for (int k2=0;k2<SLI;k2++) s += part[(bid*SLI+k2)*28 + t];
    out[4608 + bid*16 + t] = s*invd;           // state
  } else if (t<25){
    float s=0.f;
    #pragma unroll
    for (int k2=0;k2<SLI;k2++) s += part[(bid*SLI+k2)*28 + t];
    offF[t-16] = s*invd;
  }
  __syncthreads();
  if (t<9){
    const int o=t/3, x=t-o*3;
    const float cac = xyz[(bid*3+1)*3+x];
    const float CA = cac + offF[3+x];          // offset[:,:,1]
    const float v = (o==1)? CA : (CA + offF[o*3+x]);
    out[bid*9 + t] = v;                        // xyz_new
  }
}

extern "C" void kernel_launch(void* const* d_in, const int* in_sizes, int n_in,
                              void* d_out, int out_size, void* d_ws, size_t ws_size,
                              hipStream_t stream)
{
  const float* msa     = (const float*)d_in[0];
  const float* pair    = (const float*)d_in[1];
  const float* xyz     = (const float*)d_in[2];
  const float* seq1hot = (const float*)d_in[3];
  const float* g_msa   = (const float*)d_in[4];
  const float* b_msa   = (const float*)d_in[5];
  const float* g_pair  = (const float*)d_in[6];
  const float* b_pair  = (const float*)d_in[7];
  const float* Wq      = (const float*)d_in[8];
  const float* bq      = (const float*)d_in[9];
  const float* Wk      = (const float*)d_in[10];
  const float* bk      = (const float*)d_in[11];
  const float* Wx      = (const float*)d_in[12];
  const float* bx      = (const float*)d_in[13];
  const float* g_node  = (const float*)d_in[14];
  const float* b_node  = (const float*)d_in[15];
  const float* We      = (const float*)d_in[16];
  const float* be      = (const float*)d_in[17];
  const float* g_edge  = (const float*)d_in[18];
  const float* b_edge  = (const float*)d_in[19];
  const float* Wa      = (const float*)d_in[20];
  const float* ba      = (const float*)d_in[21];
  const float* W0      = (const float*)d_in[22];
  const float* b0      = (const float*)d_in[23];
  const float* Wc1     = (const float*)d_in[24];
  const float* Wc2     = (const float*)d_in[25];
  const int*   idx     = (const int*)d_in[26];
  const int*   topk    = (const int*)d_in[27];
  float* out = (float*)d_out;

  float* wsf = (float*)d_ws;
  float*    node  = wsf + WS_NODE;
  int*      cnt   = (int*)(wsf + WS_CNT);
  int*      jlist = (int*)(wsf + WS_JLIST);
  float*    m0bG  = wsf + WS_M0B;
  float*    partb = wsf + WS_PART;
  unsigned* packW = (unsigned*)(wsf + WS_PACKW);

  k_prep<<<512, 512, 0, stream>>>(msa, seq1hot, xyz, idx, topk, g_msa, b_msa,
                                  Wq, bq, Wk, bk, Wx, bx, g_node, b_node,
                                  We, Wa, W0, b0, Wc1, Wc2,
                                  node, cnt, jlist, m0bG, packW);
  k_main<<<512*SLI/4, 256, 0, stream>>>(pair, xyz, g_pair, b_pair, be, g_edge,
                                        b_edge, ba, node, cnt, jlist, m0bG,
                                        packW, partb);
  k_fin<<<512, 64, 0, stream>>>(xyz, cnt, partb, out);
}